// Round 23
// baseline (180.039 us; speedup 1.0000x reference)
//
#include <hip/hip_runtime.h>

typedef unsigned short u16t;
typedef unsigned int   u32t;
typedef __attribute__((ext_vector_type(8))) short short8;
typedef __attribute__((ext_vector_type(4))) float f32x4;

#define B_    2
#define QN    2304
#define NQ    4608
#define HWS   64
#define ENCC  64
#define DIMC  192
#define NHEAD 8
#define DKH   24
#define RAW   49
#define CFC   64
#define FRP   68       // padded fr_lds row stride (floats)
#define CMAP  640      // 192(q)+192(k)+192(v)+64(f)
#define KCONV 576      // 9*64, k = tap*64+ic
#define INDIM 15682
#define KPAD  16128    // F row stride (bf16), 252*64 = 12*1344
#define HIDN  256
#define PIX   8192     // B*64*64
#define SPLITK 12
#define KSLICE (KPAD/SPLITK)   // 1344 = 21*64

__device__ __forceinline__ float b2f(u16t u){ u32t v=((u32t)u)<<16; return __builtin_bit_cast(float,v); }
__device__ __forceinline__ u16t f2b(float f){ u32t v=__builtin_bit_cast(u32t,f); return (u16t)((v + 0x7FFFu + ((v>>16)&1u))>>16); }

#define GLOAD16(SRC, DST) __builtin_amdgcn_global_load_lds( \
  (const __attribute__((address_space(1))) unsigned int*)(const void*)(SRC), \
  (__attribute__((address_space(3))) unsigned int*)(void*)(DST), 16, 0, 0)

// ---------------- encoder conv 3->64 (f32 in), channel-last bf16 out -----------
__global__ __launch_bounds__(256) void k_enc(const float* __restrict__ inp, const float* __restrict__ ew,
                      const float* __restrict__ eb, u16t* __restrict__ feat){
  int i = blockIdx.x*256+threadIdx.x;
  if(i>=B_*HWS*HWS*ENCC) return;
  int oc=i&63, x=(i>>6)&63, y=(i>>12)&63, b=i>>18;
  float acc = eb[oc];
  for(int c=0;c<3;c++)
    for(int dy=0;dy<3;dy++){
      int yy=y+dy-1; if(yy<0||yy>=HWS) continue;
      for(int dx=0;dx<3;dx++){
        int xx=x+dx-1; if(xx<0||xx>=HWS) continue;
        acc += inp[((b*3+c)*HWS+yy)*HWS+xx] * ew[((oc*3+c)*3+dy)*3+dx];
      }
    }
  feat[i]=f2b(acc);
}

// ---------------- w1 transpose: w1[k][256] (f32) -> w1t[n][KPAD] (bf16, pad) ---
__global__ __launch_bounds__(256) void k_w1t(const float* __restrict__ w1, u16t* __restrict__ w1t){
  __shared__ u16t t[64][65];
  int kb = blockIdx.x*64, nb = blockIdx.y*64;
  for(int i=threadIdx.x;i<4096;i+=256){
    int k=i>>6, n=i&63; int gk=kb+k;
    t[k][n] = (gk<INDIM) ? f2b(w1[(size_t)gk*HIDN + nb + n]) : (u16t)0;
  }
  __syncthreads();
  for(int i=threadIdx.x;i<4096;i+=256){
    int n=i>>6, k=i&63;
    w1t[(size_t)(nb+n)*KPAD + kb + k] = t[k][n];
  }
}

// ------------- pack conv weights (f32 -> bf16, tap-major K) + biases (f32) -----
__global__ __launch_bounds__(256) void k_wconv(const float* qw,const float* kw,const float* vw,const float* fw,
                        const float* qb,const float* kb_,const float* vb,const float* fb,
                        u16t* __restrict__ wct, float* __restrict__ bias){
  int i = blockIdx.x*256+threadIdx.x;
  if(i < CMAP*KCONV){
    int oc=i/KCONV, kk=i%KCONV;
    int ic=kk&63, tap=kk>>6;              // kk = tap*64+ic
    const float* w; int ol=oc;
    if(oc<192) w=qw;
    else if(oc<384){w=kw; ol=oc-192;}
    else if(oc<576){w=vw; ol=oc-384;}
    else {w=fw; ol=oc-576;}
    wct[(size_t)oc*KCONV + kk] = f2b(w[(ol*64+ic)*9 + tap]);
  }
  if(i<CMAP){
    bias[i] = (i<192)? qb[i] : (i<384? kb_[i-192] : (i<576? vb[i-384] : fb[i-576]));
  }
}

// ---------------- im2col: A[pix][576] bf16, k=tap*64+ic ------------------------
__global__ __launch_bounds__(256) void k_im2col(const u16t* __restrict__ feat, u16t* __restrict__ A){
  int i = blockIdx.x*256+threadIdx.x;   // (pix, k8) : 8192*72
  if(i>=PIX*72) return;
  int k8=i%72, pix=i/72;
  int tap=k8/8, ic8=(k8&7)<<3;
  int x=pix&63, y=(pix>>6)&63, b=pix>>12;
  int yy=y+tap/3-1, xx=x+tap%3-1;
  uint4 v;
  if(yy>=0&&yy<HWS&&xx>=0&&xx<HWS) v = *(const uint4*)&feat[(size_t)(((b*HWS+yy)*HWS+xx)*ENCC)+ic8];
  else v = make_uint4(0u,0u,0u,0u);
  *(uint4*)&A[(size_t)pix*KCONV + tap*64 + ic8] = v;
}

// ------- 128x128-tile MFMA GEMM, BK=64 (validated R17 config) — conv only ------
__global__ __launch_bounds__(256) void k_gemm128(const u16t* __restrict__ A, int lda,
    const u16t* __restrict__ BT, int ldb, const float* __restrict__ bias,
    void* __restrict__ Cout, int ldc, int kslice, int mode){
  __shared__ __align__(16) u16t As[128*64];
  __shared__ __align__(16) u16t Bs[128*64];
  int m0 = blockIdx.x*128, n0 = blockIdx.y*128;
  int tid = threadIdx.x;
  int wave = tid>>6, lane = tid&63;
  int wm = wave>>1, wn = wave&1;
  int kg = lane>>4, l16 = lane&15;
  int kbeg = blockIdx.z*kslice, kend = kbeg+kslice;
  f32x4 acc[4][4] = {};
  for(int k0=kbeg;k0<kend;k0+=64){
    __syncthreads();
    #pragma unroll
    for(int j=0;j<4;j++){
      int seg = (wave*4+j)*64 + lane;     // 0..1023
      int row = seg>>3, qp = seg&7;
      int q = qp ^ (row&7);               // inverse swizzle on SOURCE
      GLOAD16(&A [(size_t)(m0+row)*lda + k0 + q*8], &As[(wave*4+j)*512]);
      GLOAD16(&BT[(size_t)(n0+row)*ldb + k0 + q*8], &Bs[(wave*4+j)*512]);
    }
    __syncthreads();
    #pragma unroll
    for(int kk=0;kk<2;kk++){
      int ks = kk*4 + kg;                 // k-seg 0..7 within row
      short8 a[4], b[4];
      #pragma unroll
      for(int mf=0;mf<4;mf++){
        int row = wm*64+mf*16+l16;
        a[mf] = *(const short8*)&As[row*64 + (ks^(row&7))*8];   // swizzled read
      }
      #pragma unroll
      for(int nf=0;nf<4;nf++){
        int row = wn*64+nf*16+l16;
        b[nf] = *(const short8*)&Bs[row*64 + (ks^(row&7))*8];
      }
      #pragma unroll
      for(int mf=0;mf<4;mf++)
        #pragma unroll
        for(int nf=0;nf<4;nf++)
          acc[mf][nf] = __builtin_amdgcn_mfma_f32_16x16x32_bf16(a[mf], b[nf], acc[mf][nf], 0,0,0);
    }
  }
  int l4 = lane>>4;
  if(mode==0){
    u16t* C16 = (u16t*)Cout;
    #pragma unroll
    for(int mf=0;mf<4;mf++){
      #pragma unroll
      for(int nf=0;nf<4;nf++){
        #pragma unroll
        for(int r=0;r<4;r++){
          int gm = m0 + wm*64 + mf*16 + l4*4 + r;
          int gn = n0 + wn*64 + nf*16 + l16;
          C16[(size_t)gm*ldc+gn] = f2b(acc[mf][nf][r] + bias[gn]);
        }
      }
    }
  } else {
    u16t* C16 = (u16t*)Cout + (size_t)blockIdx.z * (size_t)(gridDim.x*128) * ldc;
    #pragma unroll
    for(int mf=0;mf<4;mf++){
      #pragma unroll
      for(int nf=0;nf<4;nf++){
        #pragma unroll
        for(int r=0;r<4;r++){
          int gm = m0 + wm*64 + mf*16 + l4*4 + r;
          int gn = n0 + wn*64 + nf*16 + l16;
          C16[(size_t)gm*ldc+gn] = f2b(acc[mf][nf][r]);
        }
      }
    }
  }
}

// ------- MLP GEMM: BM=32 x BN=256, BK=64 — 1728 blocks for latency hiding ------
__global__ __launch_bounds__(256) void k_gemmMLP(const u16t* __restrict__ A, int lda,
    const u16t* __restrict__ BT, int ldb, u16t* __restrict__ Cout, int kslice){
  __shared__ __align__(16) u16t As[32*64];    // 4 KB
  __shared__ __align__(16) u16t Bs[256*64];   // 32 KB
  int m0 = blockIdx.x*32;
  int tid = threadIdx.x;
  int wave = tid>>6, lane = tid&63;
  int kg = lane>>4, l16 = lane&15;
  int kbeg = blockIdx.z*kslice, kend = kbeg+kslice;
  f32x4 acc[2][4] = {};
  for(int k0=kbeg;k0<kend;k0+=64){
    __syncthreads();
    // stage A: 256 segs (16B), exactly 1 per thread (wave groups of 64 contiguous)
    {
      int seg = tid;                      // 0..255
      int row = seg>>3, qp = seg&7;
      int q = qp ^ (row&7);
      GLOAD16(&A[(size_t)(m0+row)*lda + k0 + q*8], &As[wave*512]);
    }
    // stage B (all 256 rows of w1t): 2048 segs: groups (wave, j=0..7)
    #pragma unroll
    for(int j=0;j<8;j++){
      int seg = (wave*8+j)*64 + lane;     // 0..2047
      int row = seg>>3, qp = seg&7;
      int q = qp ^ (row&7);
      GLOAD16(&BT[(size_t)row*ldb + k0 + q*8], &Bs[(wave*8+j)*512]);
    }
    __syncthreads();
    #pragma unroll
    for(int kk=0;kk<2;kk++){
      int ks = kk*4 + kg;
      short8 a[2], b[4];
      #pragma unroll
      for(int mf=0;mf<2;mf++){
        int row = mf*16+l16;
        a[mf] = *(const short8*)&As[row*64 + (ks^(row&7))*8];
      }
      #pragma unroll
      for(int nf=0;nf<4;nf++){
        int row = wave*64+nf*16+l16;
        b[nf] = *(const short8*)&Bs[row*64 + (ks^(row&7))*8];
      }
      #pragma unroll
      for(int mf=0;mf<2;mf++)
        #pragma unroll
        for(int nf=0;nf<4;nf++)
          acc[mf][nf] = __builtin_amdgcn_mfma_f32_16x16x32_bf16(a[mf], b[nf], acc[mf][nf], 0,0,0);
    }
  }
  int l4 = lane>>4;
  u16t* C16 = Cout + (size_t)blockIdx.z * (size_t)(gridDim.x*32) * HIDN;
  #pragma unroll
  for(int mf=0;mf<2;mf++){
    #pragma unroll
    for(int nf=0;nf<4;nf++){
      #pragma unroll
      for(int r=0;r<4;r++){
        int gm = m0 + mf*16 + l4*4 + r;
        int gn = wave*64 + nf*16 + l16;
        C16[(size_t)gm*HIDN+gn] = f2b(acc[mf][nf][r]);
      }
    }
  }
}

// ------- fused split-K reduce (bf16 partials) + w2 head + residual -------------
__global__ __launch_bounds__(256) void k_redout(const u16t* __restrict__ hidp, const float* __restrict__ b1,
                      const float* __restrict__ w2, const float* __restrict__ b2v,
                      const float* __restrict__ inp, const float* __restrict__ coord,
                      float* __restrict__ outp, int M, int q0){
  int i = blockIdx.x*256+threadIdx.x;
  if(i>=M*64) return;
  int q=i>>6, lane=i&63, n4=lane*4;
  f32x4 acc = *(const f32x4*)&b1[n4];
  for(int s=0;s<SPLITK;s++){
    uint2 t = *(const uint2*)&hidp[((size_t)s*M + q)*HIDN + n4];
    acc.x += b2f((u16t)t.x); acc.y += b2f((u16t)(t.x>>16));
    acc.z += b2f((u16t)t.y); acc.w += b2f((u16t)(t.y>>16));
  }
  float h0=fmaxf(acc.x,0.f), h1=fmaxf(acc.y,0.f), h2=fmaxf(acc.z,0.f), h3=fmaxf(acc.w,0.f);
  float p0 = h0*w2[n4*3+0] + h1*w2[(n4+1)*3+0] + h2*w2[(n4+2)*3+0] + h3*w2[(n4+3)*3+0];
  float p1 = h0*w2[n4*3+1] + h1*w2[(n4+1)*3+1] + h2*w2[(n4+2)*3+1] + h3*w2[(n4+3)*3+1];
  float p2 = h0*w2[n4*3+2] + h1*w2[(n4+1)*3+2] + h2*w2[(n4+2)*3+2] + h3*w2[(n4+3)*3+2];
  #pragma unroll
  for(int m=1;m<64;m<<=1){
    p0 += __shfl_xor(p0, m);
    p1 += __shfl_xor(p1, m);
    p2 += __shfl_xor(p2, m);
  }
  if(lane<3){
    int qg = q0 + q;
    int j = lane;
    float accj = (j==0? p0 : (j==1? p1 : p2)) + b2v[j];
    int b=qg/QN;
    float cy=coord[qg*2], cx=coord[qg*2+1];
    float py=fminf(fmaxf(((cy+1.f)*64.f-1.f)*0.5f,0.f),63.f);
    float px=fminf(fmaxf(((cx+1.f)*64.f-1.f)*0.5f,0.f),63.f);
    float y0f=floorf(py), x0f=floorf(px);
    float wy=py-y0f, wx=px-x0f;
    int y0=(int)y0f, x0=(int)x0f;
    int y1=min(y0+1,63), x1=min(x0+1,63);
    const float* ip=&inp[(size_t)(b*3+j)*4096];
    float g00=ip[y0*64+x0], g01=ip[y0*64+x1];
    float g10=ip[y1*64+x0], g11=ip[y1*64+x1];
    float res=g00*(1.f-wy)*(1.f-wx)+g01*(1.f-wy)*wx+g10*wy*(1.f-wx)+g11*wy*wx;
    outp[qg*3+j]=accj+res;
  }
}

// --------- per-query features (twiddle tables kill runtime %7) -----------------
__global__ __launch_bounds__(256,8) void k_feat(const float* __restrict__ coord, const float* __restrict__ cell,
                       const u16t* __restrict__ maps, const float* __restrict__ pbw,
                       const float* __restrict__ pbb, const float* __restrict__ pew,
                       u16t* __restrict__ F, float* __restrict__ outAttn, int q0){
  __shared__ float q_lds[DIMC];
  __shared__ float relsy[RAW], relsx[RAW];
  __shared__ int   wbase[RAW];
  __shared__ float sa[RAW][NHEAD];
  __shared__ float fr_lds[RAW*FRP];
  __shared__ float c7t[49], s7t[49];    // product-indexed: [i*7+j] = tw((i*j)%7)
  __shared__ float pewf0[CFC], pewf1[CFC];
  __shared__ float pbwf0[NHEAD], pbwf1[NHEAD], pbbf[NHEAD];

  int qg = q0 + blockIdx.x;
  int b  = qg / QN;
  int tid = threadIdx.x;
  float cy = coord[qg*2], cx = coord[qg*2+1];
  const float lo = -1.0f + 1e-6f, hi = 1.0f - 1e-6f;
  float ccy = fminf(fmaxf(cy,lo),hi), ccx = fminf(fmaxf(cx,lo),hi);
  float pyq = ((ccy+1.f)*64.f - 1.f)*0.5f, pxq = ((ccx+1.f)*64.f - 1.f)*0.5f;
  int iy = (int)rintf(pyq), ix = (int)rintf(pxq);   // round half-even == jnp.round

  if(tid < RAW){
    int ki = tid/7, kj = tid%7;
    int yy = iy + ki - 3, xx = ix + kj - 3;
    wbase[tid] = (yy>=0&&yy<64&&xx>=0&&xx<64) ? ((b*64+yy)*64+xx)*CMAP : -1;
    float ck_y = (-1.f + (float)(2*iy+1)*(1.f/64.f)) + (float)(ki-3)*(2.f/64.f);
    float ck_x = (-1.f + (float)(2*ix+1)*(1.f/64.f)) + (float)(kj-3)*(2.f/64.f);
    relsy[tid] = (cy - ck_y)*64.f;
    relsx[tid] = (cx - ck_x)*64.f;
    int m = (ki*kj)%7;
    float ang = -6.283185307179586f * (float)m / 7.f;
    c7t[tid]=cosf(ang); s7t[tid]=sinf(ang);
  }
  if(tid<CFC){ pewf0[tid]=pew[tid]; pewf1[tid]=pew[CFC+tid]; }
  if(tid<NHEAD){ pbwf0[tid]=pbw[tid]; pbwf1[tid]=pbw[NHEAD+tid]; pbbf[tid]=pbb[tid]; }
  __syncthreads();

  // q: bilinear-zeros gather of fq (maps ch [0,192), bf16)
  if(tid < DIMC){
    float y0f=floorf(pyq), x0f=floorf(pxq);
    float wy=pyq-y0f, wx=pxq-x0f;
    int y0=(int)y0f, x0=(int)x0f;
    float acc=0.f;
    for(int ty=0;ty<2;ty++) for(int tx=0;tx<2;tx++){
      int yy=y0+ty, xx=x0+tx;
      if(yy<0||yy>=64||xx<0||xx>=64) continue;
      float w=(ty? wy:1.f-wy)*(tx? wx:1.f-wx);
      acc += w * b2f(maps[(size_t)((b*64+yy)*64+xx)*CMAP + tid]);
    }
    q_lds[tid]=acc;
  }
  // fr load (maps ch [576,640), bf16, uint4 = 8ch -> 2x f32x4 into padded rows)
  for(int i=tid;i<RAW*8;i+=256){
    int k=i>>3, c8=(i&7)<<3;
    int base=wbase[k];
    f32x4 lo4={0.f,0.f,0.f,0.f}, hi4={0.f,0.f,0.f,0.f};
    if(base>=0){
      uint4 t = *(const uint4*)&maps[(size_t)base + 576 + c8];
      lo4 = f32x4{b2f((u16t)t.x), b2f((u16t)(t.x>>16)), b2f((u16t)t.y), b2f((u16t)(t.y>>16))};
      hi4 = f32x4{b2f((u16t)t.z), b2f((u16t)(t.z>>16)), b2f((u16t)t.w), b2f((u16t)(t.w>>16))};
    }
    *(f32x4*)&fr_lds[k*FRP+c8]   = lo4;
    *(f32x4*)&fr_lds[k*FRP+c8+4] = hi4;
  }
  __syncthreads();

  // sim + positional bias (k maps ch [192,384), bf16)
  for(int i=tid;i<RAW*NHEAD;i+=256){
    int k=i>>3, h=i&7;
    int base=wbase[k];
    float dot=0.f;
    if(base>=0){
      const u16t* p = &maps[(size_t)base + DIMC + h*DKH];
      for(int c8=0;c8<3;c8++){
        uint4 t = *(const uint4*)&p[c8*8];
        u32t a4[4]={t.x,t.y,t.z,t.w};
        for(int j=0;j<4;j++){
          dot += q_lds[h*DKH + c8*8 + 2*j]   * b2f((u16t)a4[j]);
          dot += q_lds[h*DKH + c8*8 + 2*j+1] * b2f((u16t)(a4[j]>>16));
        }
      }
    }
    sa[k][h] = dot/sqrtf(24.f) + relsy[k]*pbwf0[h] + relsx[k]*pbwf1[h] + pbbf[h];
  }
  __syncthreads();

  // wave-parallel softmax over k per head: 8 lanes per head, shfl_xor reduce
  if(tid < 64){
    int h = tid>>3, sub = tid&7;
    float m = -1e30f;
    for(int k=sub;k<RAW;k+=8) m = fmaxf(m, sa[k][h]);
    #pragma unroll
    for(int mm=1;mm<8;mm<<=1) m = fmaxf(m, __shfl_xor(m, mm));
    float s = 0.f;
    for(int k=sub;k<RAW;k+=8){ float e=__expf(sa[k][h]-m); sa[k][h]=e; s+=e; }
    #pragma unroll
    for(int mm=1;mm<8;mm<<=1) s += __shfl_xor(s, mm);
    float inv = 1.f/s;
    for(int k=sub;k<RAW;k+=8) sa[k][h]*=inv;
  }
  __syncthreads();
  if(qg==10 && tid<RAW) outAttn[tid] = sa[tid][0];

  size_t frow = (size_t)(qg-q0)*KPAD;
  // v * attn  (maps ch [384,576), bf16) -> F[k*320 + 0..191], uint4 writes
  for(int i=tid;i<RAW*24;i+=256){
    int k=i/24, c8=(i%24)*8;
    int base=wbase[k];
    u32t o[4]={0,0,0,0};
    if(base>=0){
      uint4 t = *(const uint4*)&maps[(size_t)base + 384 + c8];
      u32t a4[4]={t.x,t.y,t.z,t.w};
      for(int j=0;j<4;j++){
        int c0=c8+2*j;
        u16t r0=f2b(b2f((u16t)a4[j])      * sa[k][ c0   /DKH]);
        u16t r1=f2b(b2f((u16t)(a4[j]>>16))* sa[k][(c0+1)/DKH]);
        o[j] = (u32t)r0 | ((u32t)r1<<16);
      }
    }
    *(uint4*)&F[frow + (size_t)k*320 + c8] = make_uint4(o[0],o[1],o[2],o[3]);
  }
  // tail: rel_cell + zero pad to KPAD (448 entries from INDIM-2)
  for(int idx=INDIM-2+tid; idx<KPAD; idx+=256){
    u16t v=0;
    if(idx==15680) v=f2b(cell[qg*2]*64.f);
    else if(idx==15681) v=f2b(cell[qg*2+1]*64.f);
    F[frow+idx]=v;
  }

  // --- register-resident 7x7 DFT (ortho) + Fourier PE -> F[k*320+192+..] ------
  #pragma unroll
  for(int pp=0;pp<2;pp++){
    int p = tid + pp*256;
    if(p < 448){
      int v_ = p>>6, c = p&63;
      float Gr[7], Gi[7];
      #pragma unroll
      for(int a_=0;a_<7;a_++){
        float re=0.f, im=0.f;
        #pragma unroll
        for(int bb=0;bb<7;bb++){
          float f=fr_lds[(a_*7+bb)*FRP+c];
          float cc=c7t[v_*7+bb], ss=s7t[v_*7+bb];   // table: tw((v_*bb)%7)
          re += f*cc; im += f*ss;
        }
        Gr[a_]=re; Gi[a_]=im;
      }
      float pw0=pewf0[c], pw1=pewf1[c];
      #pragma unroll
      for(int u=0;u<7;u++){
        int k = u*7 + v_;
        float tr=0.f, ti=0.f;
        #pragma unroll
        for(int a_=0;a_<7;a_++){
          float cc=c7t[u*7+a_], ss=s7t[u*7+a_];     // table: tw((u*a_)%7)
          tr += Gr[a_]*cc - Gi[a_]*ss;
          ti += Gr[a_]*ss + Gi[a_]*cc;
        }
        tr*=(1.f/7.f); ti*=(1.f/7.f);
        float ph = relsy[k]*pw0 + relsx[k]*pw1;
        float sp, cp; __sincosf(ph, &sp, &cp);
        float er = cp*tr - sp*ti, ei = cp*ti + sp*tr;
        u32t pk = (u32t)f2b(er) | ((u32t)f2b(ei)<<16);
        *(u32t*)&F[frow + (size_t)k*320 + 192 + 2*c] = pk;
      }
    }
  }
}

// ---------------- marker fill (order-detection failed): out = value ------------
__global__ __launch_bounds__(256) void k_mark(float* __restrict__ outp, int n, float val){
  int i = blockIdx.x*256+threadIdx.x;
  if(i<n) outp[i]=val;
}

extern "C" void kernel_launch(void* const* d_in, const int* in_sizes, int n_in,
                              void* d_out, int out_size, void* d_ws, size_t ws_size,
                              hipStream_t stream){
  int I_inp, I_coord, I_cell, I_encw, I_encb, I_qw, I_qb, I_kw, I_kb, I_vw, I_vb,
      I_fw, I_fb, I_pbw, I_pbb, I_pew, I_w1, I_b1, I_w2, I_b2;
  bool dictOrder = (n_in==20 && in_sizes[0]==24576 && in_sizes[1]==9216 && in_sizes[3]==1728
                    && in_sizes[5]==110592 && in_sizes[16]==4014592 && in_sizes[19]==3);
  bool sortOrder = (n_in==20 && in_sizes[0]==256 && in_sizes[1]==3 && in_sizes[8]==24576
                    && in_sizes[10]==110592 && in_sizes[18]==4014592 && in_sizes[19]==768);
  if(dictOrder){
    I_inp=0; I_coord=1; I_cell=2; I_encw=3; I_encb=4; I_qw=5; I_qb=6; I_kw=7; I_kb=8;
    I_vw=9; I_vb=10; I_fw=11; I_fb=12; I_pbw=13; I_pbb=14; I_pew=15; I_w1=16; I_b1=17; I_w2=18; I_b2=19;
  } else if(sortOrder){
    I_b1=0; I_b2=1; I_cell=2; I_coord=3; I_encb=4; I_encw=5; I_fb=6; I_fw=7; I_inp=8;
    I_kb=9; I_kw=10; I_pbb=11; I_pbw=12; I_pew=13; I_qb=14; I_qw=15; I_vb=16; I_vw=17; I_w1=18; I_w2=19;
  } else {
    float mark = (float)(n_in==20 ? in_sizes[0] : 1000000+n_in);
    k_mark<<<dim3((out_size+255)/256), dim3(256), 0, stream>>>((float*)d_out, out_size, mark);
    return;
  }

  const float* inp  =(const float*)d_in[I_inp];
  const float* coord=(const float*)d_in[I_coord];
  const float* cell =(const float*)d_in[I_cell];
  const float* enc_w=(const float*)d_in[I_encw];
  const float* enc_b=(const float*)d_in[I_encb];
  const float* qw=(const float*)d_in[I_qw];
  const float* qb=(const float*)d_in[I_qb];
  const float* kw=(const float*)d_in[I_kw];
  const float* kbp=(const float*)d_in[I_kb];
  const float* vw=(const float*)d_in[I_vw];
  const float* vb=(const float*)d_in[I_vb];
  const float* fw=(const float*)d_in[I_fw];
  const float* fb=(const float*)d_in[I_fb];
  const float* pbw=(const float*)d_in[I_pbw];
  const float* pbb=(const float*)d_in[I_pbb];
  const float* pew=(const float*)d_in[I_pew];
  const float* w1=(const float*)d_in[I_w1];
  const float* b1=(const float*)d_in[I_b1];
  const float* w2=(const float*)d_in[I_w2];
  const float* b2v=(const float*)d_in[I_b2];
  float* outp=(float*)d_out;

  char* ws=(char*)d_ws;
  size_t off=0;
  auto alloc=[&](size_t bytes){ size_t o=off; off=(off+bytes+255)&~(size_t)255; return o; };
  size_t o_feat = alloc((size_t)PIX*ENCC*2);                   // 1 MB  (bf16)
  size_t o_imc  = alloc((size_t)PIX*KCONV*2);                  // 9.4 MB (bf16)
  size_t o_wct  = alloc((size_t)CMAP*KCONV*2);                 // 0.74 MB
  size_t o_cb   = alloc((size_t)CMAP*4);                       // conv bias f32
  size_t o_maps = alloc((size_t)PIX*CMAP*2);                   // 10.5 MB (bf16)
  size_t o_w1t  = alloc((size_t)HIDN*KPAD*2);                  // 8.3 MB
  size_t fixed = off;
  size_t rem = (ws_size>fixed)? ws_size-fixed : 0;
  size_t perQ = (size_t)KPAD*2 + (size_t)SPLITK*HIDN*2;        // F + hidp(bf16) per query
  long long cq = (long long)(rem/perQ);
  int chunkQ = (int)((cq/128)*128);
  if(chunkQ>NQ) chunkQ=NQ;
  size_t o_F, o_hp;
  if(chunkQ>=128){
    o_F  = alloc((size_t)chunkQ*KPAD*2);
    o_hp = alloc((size_t)SPLITK*chunkQ*HIDN*2);
  } else {
    chunkQ = 128;                                              // alias imc (dead after conv GEMM)
    o_F  = o_imc;                                              // 128*KPAD*2 = 4.1 MB
    o_hp = (o_imc + (size_t)128*KPAD*2 + 255) & ~(size_t)255;  // +0.8 MB < 9.4 MB
  }

  u16t*  feat=(u16t*)(ws+o_feat);
  u16t*  imc =(u16t*)(ws+o_imc);
  u16t*  wct =(u16t*)(ws+o_wct);
  float* cbias=(float*)(ws+o_cb);
  u16t*  maps=(u16t*)(ws+o_maps);
  u16t*  w1t =(u16t*)(ws+o_w1t);
  u16t*  Fb  =(u16t*)(ws+o_F);
  u16t*  hidp=(u16t*)(ws+o_hp);

  k_w1t   <<<dim3(KPAD/64, HIDN/64), dim3(256), 0, stream>>>(w1, w1t);
  k_wconv <<<dim3((CMAP*KCONV+255)/256), dim3(256), 0, stream>>>(qw,kw,vw,fw,qb,kbp,vb,fb,wct,cbias);
  k_enc   <<<dim3((PIX*ENCC+255)/256), dim3(256), 0, stream>>>(inp,enc_w,enc_b,feat);
  k_im2col<<<dim3((PIX*72+255)/256), dim3(256), 0, stream>>>(feat,imc);
  k_gemm128<<<dim3(PIX/128, CMAP/128, 1), dim3(256), 0, stream>>>(imc, KCONV, wct, KCONV, cbias,
            (void*)maps, CMAP, KCONV, 0);

  for(int q0=0;q0<NQ;q0+=chunkQ){
    int nq = (NQ-q0 < chunkQ) ? (NQ-q0) : chunkQ;
    k_feat<<<dim3(nq), dim3(256), 0, stream>>>(coord,cell,maps,pbw,pbb,pew,Fb,outp+13824,q0);
    k_gemmMLP<<<dim3(nq/32, 1, SPLITK), dim3(256), 0, stream>>>(Fb, KPAD, w1t, KPAD, hidp, KSLICE);
    k_redout<<<dim3((nq*64+255)/256), dim3(256), 0, stream>>>(hidp, b1, w2, b2v, inp, coord,
            outp, nq, q0);
  }
}

// Round 24
// 175.211 us; speedup vs baseline: 1.0276x; 1.0276x over previous
//
#include <hip/hip_runtime.h>

typedef unsigned short u16t;
typedef unsigned int   u32t;
typedef __attribute__((ext_vector_type(8))) short short8;
typedef __attribute__((ext_vector_type(4))) float f32x4;

#define B_    2
#define QN    2304
#define NQ    4608
#define HWS   64
#define ENCC  64
#define DIMC  192
#define NHEAD 8
#define DKH   24
#define RAW   49
#define CFC   64
#define FRP   68       // padded fr_lds row stride (floats)
#define CMAP  640      // 192(q)+192(k)+192(v)+64(f)
#define KCONV 576      // 9*64, k = tap*64+ic
#define INDIM 15682
#define KPAD  16128    // F row stride (bf16), 252*64 = 12*1344
#define HIDN  256
#define PIX   8192     // B*64*64
#define SPLITK 12
#define KSLICE (KPAD/SPLITK)   // 1344 = 21*64

__device__ __forceinline__ float b2f(u16t u){ u32t v=((u32t)u)<<16; return __builtin_bit_cast(float,v); }
__device__ __forceinline__ u16t f2b(float f){ u32t v=__builtin_bit_cast(u32t,f); return (u16t)((v + 0x7FFFu + ((v>>16)&1u))>>16); }

#define GLOAD16(SRC, DST) __builtin_amdgcn_global_load_lds( \
  (const __attribute__((address_space(1))) unsigned int*)(const void*)(SRC), \
  (__attribute__((address_space(3))) unsigned int*)(void*)(DST), 16, 0, 0)

// ---------------- encoder conv 3->64 (f32 in), channel-last bf16 out -----------
__global__ __launch_bounds__(256) void k_enc(const float* __restrict__ inp, const float* __restrict__ ew,
                      const float* __restrict__ eb, u16t* __restrict__ feat){
  int i = blockIdx.x*256+threadIdx.x;
  if(i>=B_*HWS*HWS*ENCC) return;
  int oc=i&63, x=(i>>6)&63, y=(i>>12)&63, b=i>>18;
  float acc = eb[oc];
  for(int c=0;c<3;c++)
    for(int dy=0;dy<3;dy++){
      int yy=y+dy-1; if(yy<0||yy>=HWS) continue;
      for(int dx=0;dx<3;dx++){
        int xx=x+dx-1; if(xx<0||xx>=HWS) continue;
        acc += inp[((b*3+c)*HWS+yy)*HWS+xx] * ew[((oc*3+c)*3+dy)*3+dx];
      }
    }
  feat[i]=f2b(acc);
}

// ---------------- w1 transpose: w1[k][256] (f32) -> w1t[n][KPAD] (bf16, pad) ---
__global__ __launch_bounds__(256) void k_w1t(const float* __restrict__ w1, u16t* __restrict__ w1t){
  __shared__ u16t t[64][65];
  int kb = blockIdx.x*64, nb = blockIdx.y*64;
  for(int i=threadIdx.x;i<4096;i+=256){
    int k=i>>6, n=i&63; int gk=kb+k;
    t[k][n] = (gk<INDIM) ? f2b(w1[(size_t)gk*HIDN + nb + n]) : (u16t)0;
  }
  __syncthreads();
  for(int i=threadIdx.x;i<4096;i+=256){
    int n=i>>6, k=i&63;
    w1t[(size_t)(nb+n)*KPAD + kb + k] = t[k][n];
  }
}

// ------------- pack conv weights (f32 -> bf16, tap-major K) + biases (f32) -----
__global__ __launch_bounds__(256) void k_wconv(const float* qw,const float* kw,const float* vw,const float* fw,
                        const float* qb,const float* kb_,const float* vb,const float* fb,
                        u16t* __restrict__ wct, float* __restrict__ bias){
  int i = blockIdx.x*256+threadIdx.x;
  if(i < CMAP*KCONV){
    int oc=i/KCONV, kk=i%KCONV;
    int ic=kk&63, tap=kk>>6;              // kk = tap*64+ic
    const float* w; int ol=oc;
    if(oc<192) w=qw;
    else if(oc<384){w=kw; ol=oc-192;}
    else if(oc<576){w=vw; ol=oc-384;}
    else {w=fw; ol=oc-576;}
    wct[(size_t)oc*KCONV + kk] = f2b(w[(ol*64+ic)*9 + tap]);
  }
  if(i<CMAP){
    bias[i] = (i<192)? qb[i] : (i<384? kb_[i-192] : (i<576? vb[i-384] : fb[i-576]));
  }
}

// ---------------- im2col: A[pix][576] bf16, k=tap*64+ic ------------------------
__global__ __launch_bounds__(256) void k_im2col(const u16t* __restrict__ feat, u16t* __restrict__ A){
  int i = blockIdx.x*256+threadIdx.x;   // (pix, k8) : 8192*72
  if(i>=PIX*72) return;
  int k8=i%72, pix=i/72;
  int tap=k8/8, ic8=(k8&7)<<3;
  int x=pix&63, y=(pix>>6)&63, b=pix>>12;
  int yy=y+tap/3-1, xx=x+tap%3-1;
  uint4 v;
  if(yy>=0&&yy<HWS&&xx>=0&&xx<HWS) v = *(const uint4*)&feat[(size_t)(((b*HWS+yy)*HWS+xx)*ENCC)+ic8];
  else v = make_uint4(0u,0u,0u,0u);
  *(uint4*)&A[(size_t)pix*KCONV + tap*64 + ic8] = v;
}

// ------- 128x128-tile MFMA GEMM, BK=64 (validated R17 config) — conv only ------
__global__ __launch_bounds__(256) void k_gemm128(const u16t* __restrict__ A, int lda,
    const u16t* __restrict__ BT, int ldb, const float* __restrict__ bias,
    void* __restrict__ Cout, int ldc, int kslice, int mode){
  __shared__ __align__(16) u16t As[128*64];
  __shared__ __align__(16) u16t Bs[128*64];
  int m0 = blockIdx.x*128, n0 = blockIdx.y*128;
  int tid = threadIdx.x;
  int wave = tid>>6, lane = tid&63;
  int wm = wave>>1, wn = wave&1;
  int kg = lane>>4, l16 = lane&15;
  int kbeg = blockIdx.z*kslice, kend = kbeg+kslice;
  f32x4 acc[4][4] = {};
  for(int k0=kbeg;k0<kend;k0+=64){
    __syncthreads();
    #pragma unroll
    for(int j=0;j<4;j++){
      int seg = (wave*4+j)*64 + lane;     // 0..1023
      int row = seg>>3, qp = seg&7;
      int q = qp ^ (row&7);               // inverse swizzle on SOURCE
      GLOAD16(&A [(size_t)(m0+row)*lda + k0 + q*8], &As[(wave*4+j)*512]);
      GLOAD16(&BT[(size_t)(n0+row)*ldb + k0 + q*8], &Bs[(wave*4+j)*512]);
    }
    __syncthreads();
    #pragma unroll
    for(int kk=0;kk<2;kk++){
      int ks = kk*4 + kg;                 // k-seg 0..7 within row
      short8 a[4], b[4];
      #pragma unroll
      for(int mf=0;mf<4;mf++){
        int row = wm*64+mf*16+l16;
        a[mf] = *(const short8*)&As[row*64 + (ks^(row&7))*8];   // swizzled read
      }
      #pragma unroll
      for(int nf=0;nf<4;nf++){
        int row = wn*64+nf*16+l16;
        b[nf] = *(const short8*)&Bs[row*64 + (ks^(row&7))*8];
      }
      #pragma unroll
      for(int mf=0;mf<4;mf++)
        #pragma unroll
        for(int nf=0;nf<4;nf++)
          acc[mf][nf] = __builtin_amdgcn_mfma_f32_16x16x32_bf16(a[mf], b[nf], acc[mf][nf], 0,0,0);
    }
  }
  int l4 = lane>>4;
  if(mode==0){
    u16t* C16 = (u16t*)Cout;
    #pragma unroll
    for(int mf=0;mf<4;mf++){
      #pragma unroll
      for(int nf=0;nf<4;nf++){
        #pragma unroll
        for(int r=0;r<4;r++){
          int gm = m0 + wm*64 + mf*16 + l4*4 + r;
          int gn = n0 + wn*64 + nf*16 + l16;
          C16[(size_t)gm*ldc+gn] = f2b(acc[mf][nf][r] + bias[gn]);
        }
      }
    }
  } else {
    u16t* C16 = (u16t*)Cout + (size_t)blockIdx.z * (size_t)(gridDim.x*128) * ldc;
    #pragma unroll
    for(int mf=0;mf<4;mf++){
      #pragma unroll
      for(int nf=0;nf<4;nf++){
        #pragma unroll
        for(int r=0;r<4;r++){
          int gm = m0 + wm*64 + mf*16 + l4*4 + r;
          int gn = n0 + wn*64 + nf*16 + l16;
          C16[(size_t)gm*ldc+gn] = f2b(acc[mf][nf][r]);
        }
      }
    }
  }
}

// ------- MLP GEMM: BM=64 x BN=256 (full-N tile => F read ONCE), BK=64 ----------
__global__ __launch_bounds__(256) void k_gemmMLP(const u16t* __restrict__ A, int lda,
    const u16t* __restrict__ BT, int ldb, u16t* __restrict__ Cout, int kslice){
  __shared__ __align__(16) u16t As[64*64];    // 8 KB
  __shared__ __align__(16) u16t Bs[256*64];   // 32 KB
  int m0 = blockIdx.x*64;
  int tid = threadIdx.x;
  int wave = tid>>6, lane = tid&63;
  int kg = lane>>4, l16 = lane&15;
  int kbeg = blockIdx.z*kslice, kend = kbeg+kslice;
  f32x4 acc[4][4] = {};
  for(int k0=kbeg;k0<kend;k0+=64){
    __syncthreads();
    #pragma unroll
    for(int j=0;j<2;j++){
      int seg = (wave*2+j)*64 + lane;     // 0..511
      int row = seg>>3, qp = seg&7;
      int q = qp ^ (row&7);
      GLOAD16(&A[(size_t)(m0+row)*lda + k0 + q*8], &As[(wave*2+j)*512]);
    }
    #pragma unroll
    for(int j=0;j<8;j++){
      int seg = (wave*8+j)*64 + lane;     // 0..2047
      int row = seg>>3, qp = seg&7;
      int q = qp ^ (row&7);
      GLOAD16(&BT[(size_t)row*ldb + k0 + q*8], &Bs[(wave*8+j)*512]);
    }
    __syncthreads();
    #pragma unroll
    for(int kk=0;kk<2;kk++){
      int ks = kk*4 + kg;
      short8 a[4], b[4];
      #pragma unroll
      for(int mf=0;mf<4;mf++){
        int row = mf*16+l16;
        a[mf] = *(const short8*)&As[row*64 + (ks^(row&7))*8];
      }
      #pragma unroll
      for(int nf=0;nf<4;nf++){
        int row = wave*64+nf*16+l16;
        b[nf] = *(const short8*)&Bs[row*64 + (ks^(row&7))*8];
      }
      #pragma unroll
      for(int mf=0;mf<4;mf++)
        #pragma unroll
        for(int nf=0;nf<4;nf++)
          acc[mf][nf] = __builtin_amdgcn_mfma_f32_16x16x32_bf16(a[mf], b[nf], acc[mf][nf], 0,0,0);
    }
  }
  int l4 = lane>>4;
  u16t* C16 = Cout + (size_t)blockIdx.z * (size_t)(gridDim.x*64) * HIDN;
  #pragma unroll
  for(int mf=0;mf<4;mf++){
    #pragma unroll
    for(int nf=0;nf<4;nf++){
      #pragma unroll
      for(int r=0;r<4;r++){
        int gm = m0 + mf*16 + l4*4 + r;
        int gn = wave*64 + nf*16 + l16;
        C16[(size_t)gm*HIDN+gn] = f2b(acc[mf][nf][r]);
      }
    }
  }
}

// ------- fused split-K reduce (bf16 partials) + w2 head + residual -------------
__global__ __launch_bounds__(256) void k_redout(const u16t* __restrict__ hidp, const float* __restrict__ b1,
                      const float* __restrict__ w2, const float* __restrict__ b2v,
                      const float* __restrict__ inp, const float* __restrict__ coord,
                      float* __restrict__ outp, int M, int q0){
  int i = blockIdx.x*256+threadIdx.x;
  if(i>=M*64) return;
  int q=i>>6, lane=i&63, n4=lane*4;
  f32x4 acc = *(const f32x4*)&b1[n4];
  for(int s=0;s<SPLITK;s++){
    uint2 t = *(const uint2*)&hidp[((size_t)s*M + q)*HIDN + n4];
    acc.x += b2f((u16t)t.x); acc.y += b2f((u16t)(t.x>>16));
    acc.z += b2f((u16t)t.y); acc.w += b2f((u16t)(t.y>>16));
  }
  float h0=fmaxf(acc.x,0.f), h1=fmaxf(acc.y,0.f), h2=fmaxf(acc.z,0.f), h3=fmaxf(acc.w,0.f);
  float p0 = h0*w2[n4*3+0] + h1*w2[(n4+1)*3+0] + h2*w2[(n4+2)*3+0] + h3*w2[(n4+3)*3+0];
  float p1 = h0*w2[n4*3+1] + h1*w2[(n4+1)*3+1] + h2*w2[(n4+2)*3+1] + h3*w2[(n4+3)*3+1];
  float p2 = h0*w2[n4*3+2] + h1*w2[(n4+1)*3+2] + h2*w2[(n4+2)*3+2] + h3*w2[(n4+3)*3+2];
  #pragma unroll
  for(int m=1;m<64;m<<=1){
    p0 += __shfl_xor(p0, m);
    p1 += __shfl_xor(p1, m);
    p2 += __shfl_xor(p2, m);
  }
  if(lane<3){
    int qg = q0 + q;
    int j = lane;
    float accj = (j==0? p0 : (j==1? p1 : p2)) + b2v[j];
    int b=qg/QN;
    float cy=coord[qg*2], cx=coord[qg*2+1];
    float py=fminf(fmaxf(((cy+1.f)*64.f-1.f)*0.5f,0.f),63.f);
    float px=fminf(fmaxf(((cx+1.f)*64.f-1.f)*0.5f,0.f),63.f);
    float y0f=floorf(py), x0f=floorf(px);
    float wy=py-y0f, wx=px-x0f;
    int y0=(int)y0f, x0=(int)x0f;
    int y1=min(y0+1,63), x1=min(x0+1,63);
    const float* ip=&inp[(size_t)(b*3+j)*4096];
    float g00=ip[y0*64+x0], g01=ip[y0*64+x1];
    float g10=ip[y1*64+x0], g11=ip[y1*64+x1];
    float res=g00*(1.f-wy)*(1.f-wx)+g01*(1.f-wy)*wx+g10*wy*(1.f-wx)+g11*wy*wx;
    outp[qg*3+j]=accj+res;
  }
}

// --------- per-query features (twiddle tables kill runtime %7) -----------------
__global__ __launch_bounds__(256,8) void k_feat(const float* __restrict__ coord, const float* __restrict__ cell,
                       const u16t* __restrict__ maps, const float* __restrict__ pbw,
                       const float* __restrict__ pbb, const float* __restrict__ pew,
                       u16t* __restrict__ F, float* __restrict__ outAttn, int q0){
  __shared__ float q_lds[DIMC];
  __shared__ float relsy[RAW], relsx[RAW];
  __shared__ int   wbase[RAW];
  __shared__ float sa[RAW][NHEAD];
  __shared__ float fr_lds[RAW*FRP];
  __shared__ float c7t[49], s7t[49];    // product-indexed: [i*7+j] = tw((i*j)%7)
  __shared__ float pewf0[CFC], pewf1[CFC];
  __shared__ float pbwf0[NHEAD], pbwf1[NHEAD], pbbf[NHEAD];

  int qg = q0 + blockIdx.x;
  int b  = qg / QN;
  int tid = threadIdx.x;
  float cy = coord[qg*2], cx = coord[qg*2+1];
  const float lo = -1.0f + 1e-6f, hi = 1.0f - 1e-6f;
  float ccy = fminf(fmaxf(cy,lo),hi), ccx = fminf(fmaxf(cx,lo),hi);
  float pyq = ((ccy+1.f)*64.f - 1.f)*0.5f, pxq = ((ccx+1.f)*64.f - 1.f)*0.5f;
  int iy = (int)rintf(pyq), ix = (int)rintf(pxq);   // round half-even == jnp.round

  if(tid < RAW){
    int ki = tid/7, kj = tid%7;
    int yy = iy + ki - 3, xx = ix + kj - 3;
    wbase[tid] = (yy>=0&&yy<64&&xx>=0&&xx<64) ? ((b*64+yy)*64+xx)*CMAP : -1;
    float ck_y = (-1.f + (float)(2*iy+1)*(1.f/64.f)) + (float)(ki-3)*(2.f/64.f);
    float ck_x = (-1.f + (float)(2*ix+1)*(1.f/64.f)) + (float)(kj-3)*(2.f/64.f);
    relsy[tid] = (cy - ck_y)*64.f;
    relsx[tid] = (cx - ck_x)*64.f;
    int m = (ki*kj)%7;
    float ang = -6.283185307179586f * (float)m / 7.f;
    c7t[tid]=cosf(ang); s7t[tid]=sinf(ang);
  }
  if(tid<CFC){ pewf0[tid]=pew[tid]; pewf1[tid]=pew[CFC+tid]; }
  if(tid<NHEAD){ pbwf0[tid]=pbw[tid]; pbwf1[tid]=pbw[NHEAD+tid]; pbbf[tid]=pbb[tid]; }
  __syncthreads();

  // q: bilinear-zeros gather of fq (maps ch [0,192), bf16)
  if(tid < DIMC){
    float y0f=floorf(pyq), x0f=floorf(pxq);
    float wy=pyq-y0f, wx=pxq-x0f;
    int y0=(int)y0f, x0=(int)x0f;
    float acc=0.f;
    for(int ty=0;ty<2;ty++) for(int tx=0;tx<2;tx++){
      int yy=y0+ty, xx=x0+tx;
      if(yy<0||yy>=64||xx<0||xx>=64) continue;
      float w=(ty? wy:1.f-wy)*(tx? wx:1.f-wx);
      acc += w * b2f(maps[(size_t)((b*64+yy)*64+xx)*CMAP + tid]);
    }
    q_lds[tid]=acc;
  }
  // fr load (maps ch [576,640), bf16, uint4 = 8ch -> 2x f32x4 into padded rows)
  for(int i=tid;i<RAW*8;i+=256){
    int k=i>>3, c8=(i&7)<<3;
    int base=wbase[k];
    f32x4 lo4={0.f,0.f,0.f,0.f}, hi4={0.f,0.f,0.f,0.f};
    if(base>=0){
      uint4 t = *(const uint4*)&maps[(size_t)base + 576 + c8];
      lo4 = f32x4{b2f((u16t)t.x), b2f((u16t)(t.x>>16)), b2f((u16t)t.y), b2f((u16t)(t.y>>16))};
      hi4 = f32x4{b2f((u16t)t.z), b2f((u16t)(t.z>>16)), b2f((u16t)t.w), b2f((u16t)(t.w>>16))};
    }
    *(f32x4*)&fr_lds[k*FRP+c8]   = lo4;
    *(f32x4*)&fr_lds[k*FRP+c8+4] = hi4;
  }
  __syncthreads();

  // sim + positional bias (k maps ch [192,384), bf16)
  for(int i=tid;i<RAW*NHEAD;i+=256){
    int k=i>>3, h=i&7;
    int base=wbase[k];
    float dot=0.f;
    if(base>=0){
      const u16t* p = &maps[(size_t)base + DIMC + h*DKH];
      for(int c8=0;c8<3;c8++){
        uint4 t = *(const uint4*)&p[c8*8];
        u32t a4[4]={t.x,t.y,t.z,t.w};
        for(int j=0;j<4;j++){
          dot += q_lds[h*DKH + c8*8 + 2*j]   * b2f((u16t)a4[j]);
          dot += q_lds[h*DKH + c8*8 + 2*j+1] * b2f((u16t)(a4[j]>>16));
        }
      }
    }
    sa[k][h] = dot/sqrtf(24.f) + relsy[k]*pbwf0[h] + relsx[k]*pbwf1[h] + pbbf[h];
  }
  __syncthreads();

  // wave-parallel softmax over k per head: 8 lanes per head, shfl_xor reduce
  if(tid < 64){
    int h = tid>>3, sub = tid&7;
    float m = -1e30f;
    for(int k=sub;k<RAW;k+=8) m = fmaxf(m, sa[k][h]);
    #pragma unroll
    for(int mm=1;mm<8;mm<<=1) m = fmaxf(m, __shfl_xor(m, mm));
    float s = 0.f;
    for(int k=sub;k<RAW;k+=8){ float e=__expf(sa[k][h]-m); sa[k][h]=e; s+=e; }
    #pragma unroll
    for(int mm=1;mm<8;mm<<=1) s += __shfl_xor(s, mm);
    float inv = 1.f/s;
    for(int k=sub;k<RAW;k+=8) sa[k][h]*=inv;
  }
  __syncthreads();
  if(qg==10 && tid<RAW) outAttn[tid] = sa[tid][0];

  size_t frow = (size_t)(qg-q0)*KPAD;
  // v * attn  (maps ch [384,576), bf16) -> F[k*320 + 0..191], uint4 writes
  for(int i=tid;i<RAW*24;i+=256){
    int k=i/24, c8=(i%24)*8;
    int base=wbase[k];
    u32t o[4]={0,0,0,0};
    if(base>=0){
      uint4 t = *(const uint4*)&maps[(size_t)base + 384 + c8];
      u32t a4[4]={t.x,t.y,t.z,t.w};
      for(int j=0;j<4;j++){
        int c0=c8+2*j;
        u16t r0=f2b(b2f((u16t)a4[j])      * sa[k][ c0   /DKH]);
        u16t r1=f2b(b2f((u16t)(a4[j]>>16))* sa[k][(c0+1)/DKH]);
        o[j] = (u32t)r0 | ((u32t)r1<<16);
      }
    }
    *(uint4*)&F[frow + (size_t)k*320 + c8] = make_uint4(o[0],o[1],o[2],o[3]);
  }
  // tail: rel_cell + zero pad to KPAD (448 entries from INDIM-2)
  for(int idx=INDIM-2+tid; idx<KPAD; idx+=256){
    u16t v=0;
    if(idx==15680) v=f2b(cell[qg*2]*64.f);
    else if(idx==15681) v=f2b(cell[qg*2+1]*64.f);
    F[frow+idx]=v;
  }

  // --- register-resident 7x7 DFT (ortho) + Fourier PE -> F[k*320+192+..] ------
  #pragma unroll
  for(int pp=0;pp<2;pp++){
    int p = tid + pp*256;
    if(p < 448){
      int v_ = p>>6, c = p&63;
      float Gr[7], Gi[7];
      #pragma unroll
      for(int a_=0;a_<7;a_++){
        float re=0.f, im=0.f;
        #pragma unroll
        for(int bb=0;bb<7;bb++){
          float f=fr_lds[(a_*7+bb)*FRP+c];
          float cc=c7t[v_*7+bb], ss=s7t[v_*7+bb];   // table: tw((v_*bb)%7)
          re += f*cc; im += f*ss;
        }
        Gr[a_]=re; Gi[a_]=im;
      }
      float pw0=pewf0[c], pw1=pewf1[c];
      #pragma unroll
      for(int u=0;u<7;u++){
        int k = u*7 + v_;
        float tr=0.f, ti=0.f;
        #pragma unroll
        for(int a_=0;a_<7;a_++){
          float cc=c7t[u*7+a_], ss=s7t[u*7+a_];     // table: tw((u*a_)%7)
          tr += Gr[a_]*cc - Gi[a_]*ss;
          ti += Gr[a_]*ss + Gi[a_]*cc;
        }
        tr*=(1.f/7.f); ti*=(1.f/7.f);
        float ph = relsy[k]*pw0 + relsx[k]*pw1;
        float sp, cp; __sincosf(ph, &sp, &cp);
        float er = cp*tr - sp*ti, ei = cp*ti + sp*tr;
        u32t pk = (u32t)f2b(er) | ((u32t)f2b(ei)<<16);
        *(u32t*)&F[frow + (size_t)k*320 + 192 + 2*c] = pk;
      }
    }
  }
}

// ---------------- marker fill (order-detection failed): out = value ------------
__global__ __launch_bounds__(256) void k_mark(float* __restrict__ outp, int n, float val){
  int i = blockIdx.x*256+threadIdx.x;
  if(i<n) outp[i]=val;
}

extern "C" void kernel_launch(void* const* d_in, const int* in_sizes, int n_in,
                              void* d_out, int out_size, void* d_ws, size_t ws_size,
                              hipStream_t stream){
  int I_inp, I_coord, I_cell, I_encw, I_encb, I_qw, I_qb, I_kw, I_kb, I_vw, I_vb,
      I_fw, I_fb, I_pbw, I_pbb, I_pew, I_w1, I_b1, I_w2, I_b2;
  bool dictOrder = (n_in==20 && in_sizes[0]==24576 && in_sizes[1]==9216 && in_sizes[3]==1728
                    && in_sizes[5]==110592 && in_sizes[16]==4014592 && in_sizes[19]==3);
  bool sortOrder = (n_in==20 && in_sizes[0]==256 && in_sizes[1]==3 && in_sizes[8]==24576
                    && in_sizes[10]==110592 && in_sizes[18]==4014592 && in_sizes[19]==768);
  if(dictOrder){
    I_inp=0; I_coord=1; I_cell=2; I_encw=3; I_encb=4; I_qw=5; I_qb=6; I_kw=7; I_kb=8;
    I_vw=9; I_vb=10; I_fw=11; I_fb=12; I_pbw=13; I_pbb=14; I_pew=15; I_w1=16; I_b1=17; I_w2=18; I_b2=19;
  } else if(sortOrder){
    I_b1=0; I_b2=1; I_cell=2; I_coord=3; I_encb=4; I_encw=5; I_fb=6; I_fw=7; I_inp=8;
    I_kb=9; I_kw=10; I_pbb=11; I_pbw=12; I_pew=13; I_qb=14; I_qw=15; I_vb=16; I_vw=17; I_w1=18; I_w2=19;
  } else {
    float mark = (float)(n_in==20 ? in_sizes[0] : 1000000+n_in);
    k_mark<<<dim3((out_size+255)/256), dim3(256), 0, stream>>>((float*)d_out, out_size, mark);
    return;
  }

  const float* inp  =(const float*)d_in[I_inp];
  const float* coord=(const float*)d_in[I_coord];
  const float* cell =(const float*)d_in[I_cell];
  const float* enc_w=(const float*)d_in[I_encw];
  const float* enc_b=(const float*)d_in[I_encb];
  const float* qw=(const float*)d_in[I_qw];
  const float* qb=(const float*)d_in[I_qb];
  const float* kw=(const float*)d_in[I_kw];
  const float* kbp=(const float*)d_in[I_kb];
  const float* vw=(const float*)d_in[I_vw];
  const float* vb=(const float*)d_in[I_vb];
  const float* fw=(const float*)d_in[I_fw];
  const float* fb=(const float*)d_in[I_fb];
  const float* pbw=(const float*)d_in[I_pbw];
  const float* pbb=(const float*)d_in[I_pbb];
  const float* pew=(const float*)d_in[I_pew];
  const float* w1=(const float*)d_in[I_w1];
  const float* b1=(const float*)d_in[I_b1];
  const float* w2=(const float*)d_in[I_w2];
  const float* b2v=(const float*)d_in[I_b2];
  float* outp=(float*)d_out;

  char* ws=(char*)d_ws;
  size_t off=0;
  auto alloc=[&](size_t bytes){ size_t o=off; off=(off+bytes+255)&~(size_t)255; return o; };
  size_t o_feat = alloc((size_t)PIX*ENCC*2);                   // 1 MB  (bf16)
  size_t o_imc  = alloc((size_t)PIX*KCONV*2);                  // 9.4 MB (bf16)
  size_t o_wct  = alloc((size_t)CMAP*KCONV*2);                 // 0.74 MB
  size_t o_cb   = alloc((size_t)CMAP*4);                       // conv bias f32
  size_t o_maps = alloc((size_t)PIX*CMAP*2);                   // 10.5 MB (bf16)
  size_t o_w1t  = alloc((size_t)HIDN*KPAD*2);                  // 8.3 MB
  size_t fixed = off;
  size_t rem = (ws_size>fixed)? ws_size-fixed : 0;
  size_t perQ = (size_t)KPAD*2 + (size_t)SPLITK*HIDN*2;        // F + hidp(bf16) per query
  long long cq = (long long)(rem/perQ);
  int chunkQ = (int)((cq/128)*128);
  if(chunkQ>NQ) chunkQ=NQ;
  size_t o_F, o_hp;
  if(chunkQ>=128){
    o_F  = alloc((size_t)chunkQ*KPAD*2);
    o_hp = alloc((size_t)SPLITK*chunkQ*HIDN*2);
  } else {
    chunkQ = 128;                                              // alias imc (dead after conv GEMM)
    o_F  = o_imc;                                              // 128*KPAD*2 = 4.1 MB
    o_hp = (o_imc + (size_t)128*KPAD*2 + 255) & ~(size_t)255;  // +0.8 MB < 9.4 MB
  }

  u16t*  feat=(u16t*)(ws+o_feat);
  u16t*  imc =(u16t*)(ws+o_imc);
  u16t*  wct =(u16t*)(ws+o_wct);
  float* cbias=(float*)(ws+o_cb);
  u16t*  maps=(u16t*)(ws+o_maps);
  u16t*  w1t =(u16t*)(ws+o_w1t);
  u16t*  Fb  =(u16t*)(ws+o_F);
  u16t*  hidp=(u16t*)(ws+o_hp);

  k_w1t   <<<dim3(KPAD/64, HIDN/64), dim3(256), 0, stream>>>(w1, w1t);
  k_wconv <<<dim3((CMAP*KCONV+255)/256), dim3(256), 0, stream>>>(qw,kw,vw,fw,qb,kbp,vb,fb,wct,cbias);
  k_enc   <<<dim3((PIX*ENCC+255)/256), dim3(256), 0, stream>>>(inp,enc_w,enc_b,feat);
  k_im2col<<<dim3((PIX*72+255)/256), dim3(256), 0, stream>>>(feat,imc);
  k_gemm128<<<dim3(PIX/128, CMAP/128, 1), dim3(256), 0, stream>>>(imc, KCONV, wct, KCONV, cbias,
            (void*)maps, CMAP, KCONV, 0);

  for(int q0=0;q0<NQ;q0+=chunkQ){
    int nq = (NQ-q0 < chunkQ) ? (NQ-q0) : chunkQ;
    k_feat<<<dim3(nq), dim3(256), 0, stream>>>(coord,cell,maps,pbw,pbb,pew,Fb,outp+13824,q0);
    k_gemmMLP<<<dim3(nq/64, 1, SPLITK), dim3(256), 0, stream>>>(Fb, KPAD, w1t, KPAD, hidp, KSLICE);
    k_redout<<<dim3((nq*64+255)/256), dim3(256), 0, stream>>>(hidp, b1, w2, b2v, inp, coord,
            outp, nq, q0);
  }
}

// Round 25
// 170.731 us; speedup vs baseline: 1.0545x; 1.0262x over previous
//
#include <hip/hip_runtime.h>

typedef unsigned short u16t;
typedef unsigned int   u32t;
typedef __attribute__((ext_vector_type(8))) short short8;
typedef __attribute__((ext_vector_type(4))) float f32x4;

#define B_    2
#define QN    2304
#define NQ    4608
#define HWS   64
#define ENCC  64
#define DIMC  192
#define NHEAD 8
#define DKH   24
#define RAW   49
#define CFC   64
#define FRP   68       // padded fr_lds row stride (floats)
#define CMAP  640      // 192(q)+192(k)+192(v)+64(f)
#define KCONV 576      // 9*64, k = tap*64+ic
#define INDIM 15682
#define KPAD  16128    // F row stride (bf16), 252*64 = 12*1344
#define HIDN  256
#define PIX   8192     // B*64*64
#define SPLITK 12
#define KSLICE (KPAD/SPLITK)   // 1344 = 21*64

__device__ __forceinline__ float b2f(u16t u){ u32t v=((u32t)u)<<16; return __builtin_bit_cast(float,v); }
__device__ __forceinline__ u16t f2b(float f){ u32t v=__builtin_bit_cast(u32t,f); return (u16t)((v + 0x7FFFu + ((v>>16)&1u))>>16); }

#define GLOAD16(SRC, DST) __builtin_amdgcn_global_load_lds( \
  (const __attribute__((address_space(1))) unsigned int*)(const void*)(SRC), \
  (__attribute__((address_space(3))) unsigned int*)(void*)(DST), 16, 0, 0)

// ---------------- encoder conv 3->64 (f32 in), channel-last bf16 out -----------
__global__ __launch_bounds__(256) void k_enc(const float* __restrict__ inp, const float* __restrict__ ew,
                      const float* __restrict__ eb, u16t* __restrict__ feat){
  int i = blockIdx.x*256+threadIdx.x;
  if(i>=B_*HWS*HWS*ENCC) return;
  int oc=i&63, x=(i>>6)&63, y=(i>>12)&63, b=i>>18;
  float acc = eb[oc];
  for(int c=0;c<3;c++)
    for(int dy=0;dy<3;dy++){
      int yy=y+dy-1; if(yy<0||yy>=HWS) continue;
      for(int dx=0;dx<3;dx++){
        int xx=x+dx-1; if(xx<0||xx>=HWS) continue;
        acc += inp[((b*3+c)*HWS+yy)*HWS+xx] * ew[((oc*3+c)*3+dy)*3+dx];
      }
    }
  feat[i]=f2b(acc);
}

// ---------------- w1 transpose: w1[k][256] (f32) -> w1t[n][KPAD] (bf16, pad) ---
__global__ __launch_bounds__(256) void k_w1t(const float* __restrict__ w1, u16t* __restrict__ w1t){
  __shared__ u16t t[64][65];
  int kb = blockIdx.x*64, nb = blockIdx.y*64;
  for(int i=threadIdx.x;i<4096;i+=256){
    int k=i>>6, n=i&63; int gk=kb+k;
    t[k][n] = (gk<INDIM) ? f2b(w1[(size_t)gk*HIDN + nb + n]) : (u16t)0;
  }
  __syncthreads();
  for(int i=threadIdx.x;i<4096;i+=256){
    int n=i>>6, k=i&63;
    w1t[(size_t)(nb+n)*KPAD + kb + k] = t[k][n];
  }
}

// ------------- pack conv weights (f32 -> bf16, tap-major K) + biases (f32) -----
__global__ __launch_bounds__(256) void k_wconv(const float* qw,const float* kw,const float* vw,const float* fw,
                        const float* qb,const float* kb_,const float* vb,const float* fb,
                        u16t* __restrict__ wct, float* __restrict__ bias){
  int i = blockIdx.x*256+threadIdx.x;
  if(i < CMAP*KCONV){
    int oc=i/KCONV, kk=i%KCONV;
    int ic=kk&63, tap=kk>>6;              // kk = tap*64+ic
    const float* w; int ol=oc;
    if(oc<192) w=qw;
    else if(oc<384){w=kw; ol=oc-192;}
    else if(oc<576){w=vw; ol=oc-384;}
    else {w=fw; ol=oc-576;}
    wct[(size_t)oc*KCONV + kk] = f2b(w[(ol*64+ic)*9 + tap]);
  }
  if(i<CMAP){
    bias[i] = (i<192)? qb[i] : (i<384? kb_[i-192] : (i<576? vb[i-384] : fb[i-576]));
  }
}

// ---------------- im2col: A[pix][576] bf16, k=tap*64+ic ------------------------
__global__ __launch_bounds__(256) void k_im2col(const u16t* __restrict__ feat, u16t* __restrict__ A){
  int i = blockIdx.x*256+threadIdx.x;   // (pix, k8) : 8192*72
  if(i>=PIX*72) return;
  int k8=i%72, pix=i/72;
  int tap=k8/8, ic8=(k8&7)<<3;
  int x=pix&63, y=(pix>>6)&63, b=pix>>12;
  int yy=y+tap/3-1, xx=x+tap%3-1;
  uint4 v;
  if(yy>=0&&yy<HWS&&xx>=0&&xx<HWS) v = *(const uint4*)&feat[(size_t)(((b*HWS+yy)*HWS+xx)*ENCC)+ic8];
  else v = make_uint4(0u,0u,0u,0u);
  *(uint4*)&A[(size_t)pix*KCONV + tap*64 + ic8] = v;
}

// ------- 128x128-tile MFMA GEMM, BK=64 (validated R17 config) — conv only ------
__global__ __launch_bounds__(256) void k_gemm128(const u16t* __restrict__ A, int lda,
    const u16t* __restrict__ BT, int ldb, const float* __restrict__ bias,
    void* __restrict__ Cout, int ldc, int kslice, int mode){
  __shared__ __align__(16) u16t As[128*64];
  __shared__ __align__(16) u16t Bs[128*64];
  int m0 = blockIdx.x*128, n0 = blockIdx.y*128;
  int tid = threadIdx.x;
  int wave = tid>>6, lane = tid&63;
  int wm = wave>>1, wn = wave&1;
  int kg = lane>>4, l16 = lane&15;
  int kbeg = blockIdx.z*kslice, kend = kbeg+kslice;
  f32x4 acc[4][4] = {};
  for(int k0=kbeg;k0<kend;k0+=64){
    __syncthreads();
    #pragma unroll
    for(int j=0;j<4;j++){
      int seg = (wave*4+j)*64 + lane;     // 0..1023
      int row = seg>>3, qp = seg&7;
      int q = qp ^ (row&7);               // inverse swizzle on SOURCE
      GLOAD16(&A [(size_t)(m0+row)*lda + k0 + q*8], &As[(wave*4+j)*512]);
      GLOAD16(&BT[(size_t)(n0+row)*ldb + k0 + q*8], &Bs[(wave*4+j)*512]);
    }
    __syncthreads();
    #pragma unroll
    for(int kk=0;kk<2;kk++){
      int ks = kk*4 + kg;                 // k-seg 0..7 within row
      short8 a[4], b[4];
      #pragma unroll
      for(int mf=0;mf<4;mf++){
        int row = wm*64+mf*16+l16;
        a[mf] = *(const short8*)&As[row*64 + (ks^(row&7))*8];   // swizzled read
      }
      #pragma unroll
      for(int nf=0;nf<4;nf++){
        int row = wn*64+nf*16+l16;
        b[nf] = *(const short8*)&Bs[row*64 + (ks^(row&7))*8];
      }
      #pragma unroll
      for(int mf=0;mf<4;mf++)
        #pragma unroll
        for(int nf=0;nf<4;nf++)
          acc[mf][nf] = __builtin_amdgcn_mfma_f32_16x16x32_bf16(a[mf], b[nf], acc[mf][nf], 0,0,0);
    }
  }
  int l4 = lane>>4;
  if(mode==0){
    u16t* C16 = (u16t*)Cout;
    #pragma unroll
    for(int mf=0;mf<4;mf++){
      #pragma unroll
      for(int nf=0;nf<4;nf++){
        #pragma unroll
        for(int r=0;r<4;r++){
          int gm = m0 + wm*64 + mf*16 + l4*4 + r;
          int gn = n0 + wn*64 + nf*16 + l16;
          C16[(size_t)gm*ldc+gn] = f2b(acc[mf][nf][r] + bias[gn]);
        }
      }
    }
  } else {
    u16t* C16 = (u16t*)Cout + (size_t)blockIdx.z * (size_t)(gridDim.x*128) * ldc;
    #pragma unroll
    for(int mf=0;mf<4;mf++){
      #pragma unroll
      for(int nf=0;nf<4;nf++){
        #pragma unroll
        for(int r=0;r<4;r++){
          int gm = m0 + wm*64 + mf*16 + l4*4 + r;
          int gn = n0 + wn*64 + nf*16 + l16;
          C16[(size_t)gm*ldc+gn] = f2b(acc[mf][nf][r]);
        }
      }
    }
  }
}

// ------- MLP GEMM: BM=64 x BN=256 (full-N tile => F read ONCE), BK=64 ----------
__global__ __launch_bounds__(256) void k_gemmMLP(const u16t* __restrict__ A, int lda,
    const u16t* __restrict__ BT, int ldb, u16t* __restrict__ Cout, int kslice){
  __shared__ __align__(16) u16t As[64*64];    // 8 KB
  __shared__ __align__(16) u16t Bs[256*64];   // 32 KB
  int m0 = blockIdx.x*64;
  int tid = threadIdx.x;
  int wave = tid>>6, lane = tid&63;
  int kg = lane>>4, l16 = lane&15;
  int kbeg = blockIdx.z*kslice, kend = kbeg+kslice;
  f32x4 acc[4][4] = {};
  for(int k0=kbeg;k0<kend;k0+=64){
    __syncthreads();
    #pragma unroll
    for(int j=0;j<2;j++){
      int seg = (wave*2+j)*64 + lane;     // 0..511
      int row = seg>>3, qp = seg&7;
      int q = qp ^ (row&7);
      GLOAD16(&A[(size_t)(m0+row)*lda + k0 + q*8], &As[(wave*2+j)*512]);
    }
    #pragma unroll
    for(int j=0;j<8;j++){
      int seg = (wave*8+j)*64 + lane;     // 0..2047
      int row = seg>>3, qp = seg&7;
      int q = qp ^ (row&7);
      GLOAD16(&BT[(size_t)row*ldb + k0 + q*8], &Bs[(wave*8+j)*512]);
    }
    __syncthreads();
    #pragma unroll
    for(int kk=0;kk<2;kk++){
      int ks = kk*4 + kg;
      short8 a[4], b[4];
      #pragma unroll
      for(int mf=0;mf<4;mf++){
        int row = mf*16+l16;
        a[mf] = *(const short8*)&As[row*64 + (ks^(row&7))*8];
      }
      #pragma unroll
      for(int nf=0;nf<4;nf++){
        int row = wave*64+nf*16+l16;
        b[nf] = *(const short8*)&Bs[row*64 + (ks^(row&7))*8];
      }
      #pragma unroll
      for(int mf=0;mf<4;mf++)
        #pragma unroll
        for(int nf=0;nf<4;nf++)
          acc[mf][nf] = __builtin_amdgcn_mfma_f32_16x16x32_bf16(a[mf], b[nf], acc[mf][nf], 0,0,0);
    }
  }
  int l4 = lane>>4;
  u16t* C16 = Cout + (size_t)blockIdx.z * (size_t)(gridDim.x*64) * HIDN;
  #pragma unroll
  for(int mf=0;mf<4;mf++){
    #pragma unroll
    for(int nf=0;nf<4;nf++){
      #pragma unroll
      for(int r=0;r<4;r++){
        int gm = m0 + mf*16 + l4*4 + r;
        int gn = wave*64 + nf*16 + l16;
        C16[(size_t)gm*HIDN+gn] = f2b(acc[mf][nf][r]);
      }
    }
  }
}

// ------- fused split-K reduce (bf16 partials) + w2 head + residual -------------
__global__ __launch_bounds__(256) void k_redout(const u16t* __restrict__ hidp, const float* __restrict__ b1,
                      const float* __restrict__ w2, const float* __restrict__ b2v,
                      const float* __restrict__ inp, const float* __restrict__ coord,
                      float* __restrict__ outp, int M, int q0){
  int i = blockIdx.x*256+threadIdx.x;
  if(i>=M*64) return;
  int q=i>>6, lane=i&63, n4=lane*4;
  f32x4 acc = *(const f32x4*)&b1[n4];
  for(int s=0;s<SPLITK;s++){
    uint2 t = *(const uint2*)&hidp[((size_t)s*M + q)*HIDN + n4];
    acc.x += b2f((u16t)t.x); acc.y += b2f((u16t)(t.x>>16));
    acc.z += b2f((u16t)t.y); acc.w += b2f((u16t)(t.y>>16));
  }
  float h0=fmaxf(acc.x,0.f), h1=fmaxf(acc.y,0.f), h2=fmaxf(acc.z,0.f), h3=fmaxf(acc.w,0.f);
  float p0 = h0*w2[n4*3+0] + h1*w2[(n4+1)*3+0] + h2*w2[(n4+2)*3+0] + h3*w2[(n4+3)*3+0];
  float p1 = h0*w2[n4*3+1] + h1*w2[(n4+1)*3+1] + h2*w2[(n4+2)*3+1] + h3*w2[(n4+3)*3+1];
  float p2 = h0*w2[n4*3+2] + h1*w2[(n4+1)*3+2] + h2*w2[(n4+2)*3+2] + h3*w2[(n4+3)*3+2];
  #pragma unroll
  for(int m=1;m<64;m<<=1){
    p0 += __shfl_xor(p0, m);
    p1 += __shfl_xor(p1, m);
    p2 += __shfl_xor(p2, m);
  }
  if(lane<3){
    int qg = q0 + q;
    int j = lane;
    float accj = (j==0? p0 : (j==1? p1 : p2)) + b2v[j];
    int b=qg/QN;
    float cy=coord[qg*2], cx=coord[qg*2+1];
    float py=fminf(fmaxf(((cy+1.f)*64.f-1.f)*0.5f,0.f),63.f);
    float px=fminf(fmaxf(((cx+1.f)*64.f-1.f)*0.5f,0.f),63.f);
    float y0f=floorf(py), x0f=floorf(px);
    float wy=py-y0f, wx=px-x0f;
    int y0=(int)y0f, x0=(int)x0f;
    int y1=min(y0+1,63), x1=min(x0+1,63);
    const float* ip=&inp[(size_t)(b*3+j)*4096];
    float g00=ip[y0*64+x0], g01=ip[y0*64+x1];
    float g10=ip[y1*64+x0], g11=ip[y1*64+x1];
    float res=g00*(1.f-wy)*(1.f-wx)+g01*(1.f-wy)*wx+g10*wy*(1.f-wx)+g11*wy*wx;
    outp[qg*3+j]=accj+res;
  }
}

// --------- per-query features (Hermitian-half DFT: v in 0..3 + conjugates) -----
__global__ __launch_bounds__(256,8) void k_feat(const float* __restrict__ coord, const float* __restrict__ cell,
                       const u16t* __restrict__ maps, const float* __restrict__ pbw,
                       const float* __restrict__ pbb, const float* __restrict__ pew,
                       u16t* __restrict__ F, float* __restrict__ outAttn, int q0){
  __shared__ float q_lds[DIMC];
  __shared__ float relsy[RAW], relsx[RAW];
  __shared__ int   wbase[RAW];
  __shared__ float sa[RAW][NHEAD];
  __shared__ float fr_lds[RAW*FRP];
  __shared__ float c7t[49], s7t[49];    // product-indexed: [i*7+j] = tw((i*j)%7)
  __shared__ float pewf0[CFC], pewf1[CFC];
  __shared__ float pbwf0[NHEAD], pbwf1[NHEAD], pbbf[NHEAD];

  int qg = q0 + blockIdx.x;
  int b  = qg / QN;
  int tid = threadIdx.x;
  float cy = coord[qg*2], cx = coord[qg*2+1];
  const float lo = -1.0f + 1e-6f, hi = 1.0f - 1e-6f;
  float ccy = fminf(fmaxf(cy,lo),hi), ccx = fminf(fmaxf(cx,lo),hi);
  float pyq = ((ccy+1.f)*64.f - 1.f)*0.5f, pxq = ((ccx+1.f)*64.f - 1.f)*0.5f;
  int iy = (int)rintf(pyq), ix = (int)rintf(pxq);   // round half-even == jnp.round

  if(tid < RAW){
    int ki = tid/7, kj = tid%7;
    int yy = iy + ki - 3, xx = ix + kj - 3;
    wbase[tid] = (yy>=0&&yy<64&&xx>=0&&xx<64) ? ((b*64+yy)*64+xx)*CMAP : -1;
    float ck_y = (-1.f + (float)(2*iy+1)*(1.f/64.f)) + (float)(ki-3)*(2.f/64.f);
    float ck_x = (-1.f + (float)(2*ix+1)*(1.f/64.f)) + (float)(kj-3)*(2.f/64.f);
    relsy[tid] = (cy - ck_y)*64.f;
    relsx[tid] = (cx - ck_x)*64.f;
    int m = (ki*kj)%7;
    float ang = -6.283185307179586f * (float)m / 7.f;
    c7t[tid]=cosf(ang); s7t[tid]=sinf(ang);
  }
  if(tid<CFC){ pewf0[tid]=pew[tid]; pewf1[tid]=pew[CFC+tid]; }
  if(tid<NHEAD){ pbwf0[tid]=pbw[tid]; pbwf1[tid]=pbw[NHEAD+tid]; pbbf[tid]=pbb[tid]; }
  __syncthreads();

  // q: bilinear-zeros gather of fq (maps ch [0,192), bf16)
  if(tid < DIMC){
    float y0f=floorf(pyq), x0f=floorf(pxq);
    float wy=pyq-y0f, wx=pxq-x0f;
    int y0=(int)y0f, x0=(int)x0f;
    float acc=0.f;
    for(int ty=0;ty<2;ty++) for(int tx=0;tx<2;tx++){
      int yy=y0+ty, xx=x0+tx;
      if(yy<0||yy>=64||xx<0||xx>=64) continue;
      float w=(ty? wy:1.f-wy)*(tx? wx:1.f-wx);
      acc += w * b2f(maps[(size_t)((b*64+yy)*64+xx)*CMAP + tid]);
    }
    q_lds[tid]=acc;
  }
  // fr load (maps ch [576,640), bf16, uint4 = 8ch -> 2x f32x4 into padded rows)
  for(int i=tid;i<RAW*8;i+=256){
    int k=i>>3, c8=(i&7)<<3;
    int base=wbase[k];
    f32x4 lo4={0.f,0.f,0.f,0.f}, hi4={0.f,0.f,0.f,0.f};
    if(base>=0){
      uint4 t = *(const uint4*)&maps[(size_t)base + 576 + c8];
      lo4 = f32x4{b2f((u16t)t.x), b2f((u16t)(t.x>>16)), b2f((u16t)t.y), b2f((u16t)(t.y>>16))};
      hi4 = f32x4{b2f((u16t)t.z), b2f((u16t)(t.z>>16)), b2f((u16t)t.w), b2f((u16t)(t.w>>16))};
    }
    *(f32x4*)&fr_lds[k*FRP+c8]   = lo4;
    *(f32x4*)&fr_lds[k*FRP+c8+4] = hi4;
  }
  __syncthreads();

  // sim + positional bias (k maps ch [192,384), bf16)
  for(int i=tid;i<RAW*NHEAD;i+=256){
    int k=i>>3, h=i&7;
    int base=wbase[k];
    float dot=0.f;
    if(base>=0){
      const u16t* p = &maps[(size_t)base + DIMC + h*DKH];
      for(int c8=0;c8<3;c8++){
        uint4 t = *(const uint4*)&p[c8*8];
        u32t a4[4]={t.x,t.y,t.z,t.w};
        for(int j=0;j<4;j++){
          dot += q_lds[h*DKH + c8*8 + 2*j]   * b2f((u16t)a4[j]);
          dot += q_lds[h*DKH + c8*8 + 2*j+1] * b2f((u16t)(a4[j]>>16));
        }
      }
    }
    sa[k][h] = dot/sqrtf(24.f) + relsy[k]*pbwf0[h] + relsx[k]*pbwf1[h] + pbbf[h];
  }
  __syncthreads();

  // wave-parallel softmax over k per head: 8 lanes per head, shfl_xor reduce
  if(tid < 64){
    int h = tid>>3, sub = tid&7;
    float m = -1e30f;
    for(int k=sub;k<RAW;k+=8) m = fmaxf(m, sa[k][h]);
    #pragma unroll
    for(int mm=1;mm<8;mm<<=1) m = fmaxf(m, __shfl_xor(m, mm));
    float s = 0.f;
    for(int k=sub;k<RAW;k+=8){ float e=__expf(sa[k][h]-m); sa[k][h]=e; s+=e; }
    #pragma unroll
    for(int mm=1;mm<8;mm<<=1) s += __shfl_xor(s, mm);
    float inv = 1.f/s;
    for(int k=sub;k<RAW;k+=8) sa[k][h]*=inv;
  }
  __syncthreads();
  if(qg==10 && tid<RAW) outAttn[tid] = sa[tid][0];

  size_t frow = (size_t)(qg-q0)*KPAD;
  // v * attn  (maps ch [384,576), bf16) -> F[k*320 + 0..191], uint4 writes
  for(int i=tid;i<RAW*24;i+=256){
    int k=i/24, c8=(i%24)*8;
    int base=wbase[k];
    u32t o[4]={0,0,0,0};
    if(base>=0){
      uint4 t = *(const uint4*)&maps[(size_t)base + 384 + c8];
      u32t a4[4]={t.x,t.y,t.z,t.w};
      for(int j=0;j<4;j++){
        int c0=c8+2*j;
        u16t r0=f2b(b2f((u16t)a4[j])      * sa[k][ c0   /DKH]);
        u16t r1=f2b(b2f((u16t)(a4[j]>>16))* sa[k][(c0+1)/DKH]);
        o[j] = (u32t)r0 | ((u32t)r1<<16);
      }
    }
    *(uint4*)&F[frow + (size_t)k*320 + c8] = make_uint4(o[0],o[1],o[2],o[3]);
  }
  // tail: rel_cell + zero pad to KPAD (448 entries from INDIM-2)
  for(int idx=INDIM-2+tid; idx<KPAD; idx+=256){
    u16t v=0;
    if(idx==15680) v=f2b(cell[qg*2]*64.f);
    else if(idx==15681) v=f2b(cell[qg*2+1]*64.f);
    F[frow+idx]=v;
  }

  // --- Hermitian-half 7x7 DFT (ortho) + Fourier PE -> F[k*320+192+..] ---------
  // F(u,v) = conj(F((7-u)%7,(7-v)%7)) since fr is real. Compute v_=tid>>6 in
  // {0..3}; emit direct outputs and conjugate partners (tr2=tr, ti2=-ti).
  {
    int v_ = tid>>6, c = tid&63;          // 256 pairs, exactly 1/thread
    float Gr[7], Gi[7];
    #pragma unroll
    for(int a_=0;a_<7;a_++){
      float re=0.f, im=0.f;
      #pragma unroll
      for(int bb=0;bb<7;bb++){
        float f=fr_lds[(a_*7+bb)*FRP+c];
        float cc=c7t[v_*7+bb], ss=s7t[v_*7+bb];
        re += f*cc; im += f*ss;
      }
      Gr[a_]=re; Gi[a_]=im;
    }
    float pw0=pewf0[c], pw1=pewf1[c];
    int umax = (v_==0) ? 4 : 7;           // v=0: u=0..3 direct (+conj 4..6)
    for(int u=0;u<umax;u++){
      float tr=0.f, ti=0.f;
      #pragma unroll
      for(int a_=0;a_<7;a_++){
        float cc=c7t[u*7+a_], ss=s7t[u*7+a_];
        tr += Gr[a_]*cc - Gi[a_]*ss;
        ti += Gr[a_]*ss + Gi[a_]*cc;
      }
      tr*=(1.f/7.f); ti*=(1.f/7.f);
      // direct output at k = u*7 + v_
      {
        int k = u*7 + v_;
        float ph = relsy[k]*pw0 + relsx[k]*pw1;
        float sp, cp; __sincosf(ph, &sp, &cp);
        float er = cp*tr - sp*ti, ei = cp*ti + sp*tr;
        u32t pk = (u32t)f2b(er) | ((u32t)f2b(ei)<<16);
        *(u32t*)&F[frow + (size_t)k*320 + 192 + 2*c] = pk;
      }
      // conjugate partner at (u2, v2) = ((7-u)%7, (7-v_)%7), skip self (u=0,v=0)
      if(!(v_==0 && u==0)){
        int u2 = (7-u)%7, v2 = (7-v_)%7;
        int k2 = u2*7 + v2;
        float tr2 = tr, ti2 = -ti;
        float ph = relsy[k2]*pw0 + relsx[k2]*pw1;
        float sp, cp; __sincosf(ph, &sp, &cp);
        float er = cp*tr2 - sp*ti2, ei = cp*ti2 + sp*tr2;
        u32t pk = (u32t)f2b(er) | ((u32t)f2b(ei)<<16);
        *(u32t*)&F[frow + (size_t)k2*320 + 192 + 2*c] = pk;
      }
    }
  }
}

// ---------------- marker fill (order-detection failed): out = value ------------
__global__ __launch_bounds__(256) void k_mark(float* __restrict__ outp, int n, float val){
  int i = blockIdx.x*256+threadIdx.x;
  if(i<n) outp[i]=val;
}

extern "C" void kernel_launch(void* const* d_in, const int* in_sizes, int n_in,
                              void* d_out, int out_size, void* d_ws, size_t ws_size,
                              hipStream_t stream){
  int I_inp, I_coord, I_cell, I_encw, I_encb, I_qw, I_qb, I_kw, I_kb, I_vw, I_vb,
      I_fw, I_fb, I_pbw, I_pbb, I_pew, I_w1, I_b1, I_w2, I_b2;
  bool dictOrder = (n_in==20 && in_sizes[0]==24576 && in_sizes[1]==9216 && in_sizes[3]==1728
                    && in_sizes[5]==110592 && in_sizes[16]==4014592 && in_sizes[19]==3);
  bool sortOrder = (n_in==20 && in_sizes[0]==256 && in_sizes[1]==3 && in_sizes[8]==24576
                    && in_sizes[10]==110592 && in_sizes[18]==4014592 && in_sizes[19]==768);
  if(dictOrder){
    I_inp=0; I_coord=1; I_cell=2; I_encw=3; I_encb=4; I_qw=5; I_qb=6; I_kw=7; I_kb=8;
    I_vw=9; I_vb=10; I_fw=11; I_fb=12; I_pbw=13; I_pbb=14; I_pew=15; I_w1=16; I_b1=17; I_w2=18; I_b2=19;
  } else if(sortOrder){
    I_b1=0; I_b2=1; I_cell=2; I_coord=3; I_encb=4; I_encw=5; I_fb=6; I_fw=7; I_inp=8;
    I_kb=9; I_kw=10; I_pbb=11; I_pbw=12; I_pew=13; I_qb=14; I_qw=15; I_vb=16; I_vw=17; I_w1=18; I_w2=19;
  } else {
    float mark = (float)(n_in==20 ? in_sizes[0] : 1000000+n_in);
    k_mark<<<dim3((out_size+255)/256), dim3(256), 0, stream>>>((float*)d_out, out_size, mark);
    return;
  }

  const float* inp  =(const float*)d_in[I_inp];
  const float* coord=(const float*)d_in[I_coord];
  const float* cell =(const float*)d_in[I_cell];
  const float* enc_w=(const float*)d_in[I_encw];
  const float* enc_b=(const float*)d_in[I_encb];
  const float* qw=(const float*)d_in[I_qw];
  const float* qb=(const float*)d_in[I_qb];
  const float* kw=(const float*)d_in[I_kw];
  const float* kbp=(const float*)d_in[I_kb];
  const float* vw=(const float*)d_in[I_vw];
  const float* vb=(const float*)d_in[I_vb];
  const float* fw=(const float*)d_in[I_fw];
  const float* fb=(const float*)d_in[I_fb];
  const float* pbw=(const float*)d_in[I_pbw];
  const float* pbb=(const float*)d_in[I_pbb];
  const float* pew=(const float*)d_in[I_pew];
  const float* w1=(const float*)d_in[I_w1];
  const float* b1=(const float*)d_in[I_b1];
  const float* w2=(const float*)d_in[I_w2];
  const float* b2v=(const float*)d_in[I_b2];
  float* outp=(float*)d_out;

  char* ws=(char*)d_ws;
  size_t off=0;
  auto alloc=[&](size_t bytes){ size_t o=off; off=(off+bytes+255)&~(size_t)255; return o; };
  size_t o_feat = alloc((size_t)PIX*ENCC*2);                   // 1 MB  (bf16)
  size_t o_imc  = alloc((size_t)PIX*KCONV*2);                  // 9.4 MB (bf16)
  size_t o_wct  = alloc((size_t)CMAP*KCONV*2);                 // 0.74 MB
  size_t o_cb   = alloc((size_t)CMAP*4);                       // conv bias f32
  size_t o_maps = alloc((size_t)PIX*CMAP*2);                   // 10.5 MB (bf16)
  size_t o_w1t  = alloc((size_t)HIDN*KPAD*2);                  // 8.3 MB
  size_t fixed = off;
  size_t rem = (ws_size>fixed)? ws_size-fixed : 0;
  size_t perQ = (size_t)KPAD*2 + (size_t)SPLITK*HIDN*2;        // F + hidp(bf16) per query
  long long cq = (long long)(rem/perQ);
  int chunkQ = (int)((cq/128)*128);
  if(chunkQ>NQ) chunkQ=NQ;
  size_t o_F, o_hp;
  if(chunkQ>=128){
    o_F  = alloc((size_t)chunkQ*KPAD*2);
    o_hp = alloc((size_t)SPLITK*chunkQ*HIDN*2);
  } else {
    chunkQ = 128;                                              // alias imc (dead after conv GEMM)
    o_F  = o_imc;                                              // 128*KPAD*2 = 4.1 MB
    o_hp = (o_imc + (size_t)128*KPAD*2 + 255) & ~(size_t)255;  // +0.8 MB < 9.4 MB
  }

  u16t*  feat=(u16t*)(ws+o_feat);
  u16t*  imc =(u16t*)(ws+o_imc);
  u16t*  wct =(u16t*)(ws+o_wct);
  float* cbias=(float*)(ws+o_cb);
  u16t*  maps=(u16t*)(ws+o_maps);
  u16t*  w1t =(u16t*)(ws+o_w1t);
  u16t*  Fb  =(u16t*)(ws+o_F);
  u16t*  hidp=(u16t*)(ws+o_hp);

  k_w1t   <<<dim3(KPAD/64, HIDN/64), dim3(256), 0, stream>>>(w1, w1t);
  k_wconv <<<dim3((CMAP*KCONV+255)/256), dim3(256), 0, stream>>>(qw,kw,vw,fw,qb,kbp,vb,fb,wct,cbias);
  k_enc   <<<dim3((PIX*ENCC+255)/256), dim3(256), 0, stream>>>(inp,enc_w,enc_b,feat);
  k_im2col<<<dim3((PIX*72+255)/256), dim3(256), 0, stream>>>(feat,imc);
  k_gemm128<<<dim3(PIX/128, CMAP/128, 1), dim3(256), 0, stream>>>(imc, KCONV, wct, KCONV, cbias,
            (void*)maps, CMAP, KCONV, 0);

  for(int q0=0;q0<NQ;q0+=chunkQ){
    int nq = (NQ-q0 < chunkQ) ? (NQ-q0) : chunkQ;
    k_feat<<<dim3(nq), dim3(256), 0, stream>>>(coord,cell,maps,pbw,pbb,pew,Fb,outp+13824,q0);
    k_gemmMLP<<<dim3(nq/64, 1, SPLITK), dim3(256), 0, stream>>>(Fb, KPAD, w1t, KPAD, hidp, KSLICE);
    k_redout<<<dim3((nq*64+255)/256), dim3(256), 0, stream>>>(hidp, b1, w2, b2v, inp, coord,
            outp, nq, q0);
  }
}

// Round 26
// 170.535 us; speedup vs baseline: 1.0557x; 1.0012x over previous
//
#include <hip/hip_runtime.h>

typedef unsigned short u16t;
typedef unsigned int   u32t;
typedef __attribute__((ext_vector_type(8))) short short8;
typedef __attribute__((ext_vector_type(4))) float f32x4;

#define B_    2
#define QN    2304
#define NQ    4608
#define HWS   64
#define ENCC  64
#define DIMC  192
#define NHEAD 8
#define DKH   24
#define RAW   49
#define CFC   64
#define FRP   68       // padded fr_lds row stride (floats)
#define CMAP  640      // 192(q)+192(k)+192(v)+64(f)
#define KCONV 576      // 9*64, k = tap*64+ic
#define INDIM 15682
#define KPAD  16128    // F row stride (bf16), 252*64 = 12*1344
#define HIDN  256
#define PIX   8192     // B*64*64
#define SPLITK 12
#define KSLICE (KPAD/SPLITK)   // 1344 = 21*64

__device__ __forceinline__ float b2f(u16t u){ u32t v=((u32t)u)<<16; return __builtin_bit_cast(float,v); }
__device__ __forceinline__ u16t f2b(float f){ u32t v=__builtin_bit_cast(u32t,f); return (u16t)((v + 0x7FFFu + ((v>>16)&1u))>>16); }

#define GLOAD16(SRC, DST) __builtin_amdgcn_global_load_lds( \
  (const __attribute__((address_space(1))) unsigned int*)(const void*)(SRC), \
  (__attribute__((address_space(3))) unsigned int*)(void*)(DST), 16, 0, 0)

// ---------------- encoder conv 3->64 (f32 in), channel-last bf16 out -----------
__global__ __launch_bounds__(256) void k_enc(const float* __restrict__ inp, const float* __restrict__ ew,
                      const float* __restrict__ eb, u16t* __restrict__ feat){
  int i = blockIdx.x*256+threadIdx.x;
  if(i>=B_*HWS*HWS*ENCC) return;
  int oc=i&63, x=(i>>6)&63, y=(i>>12)&63, b=i>>18;
  float acc = eb[oc];
  for(int c=0;c<3;c++)
    for(int dy=0;dy<3;dy++){
      int yy=y+dy-1; if(yy<0||yy>=HWS) continue;
      for(int dx=0;dx<3;dx++){
        int xx=x+dx-1; if(xx<0||xx>=HWS) continue;
        acc += inp[((b*3+c)*HWS+yy)*HWS+xx] * ew[((oc*3+c)*3+dy)*3+dx];
      }
    }
  feat[i]=f2b(acc);
}

// ---------------- w1 transpose: w1[k][256] (f32) -> w1t[n][KPAD] (bf16, pad) ---
__global__ __launch_bounds__(256) void k_w1t(const float* __restrict__ w1, u16t* __restrict__ w1t){
  __shared__ u16t t[64][65];
  int kb = blockIdx.x*64, nb = blockIdx.y*64;
  for(int i=threadIdx.x;i<4096;i+=256){
    int k=i>>6, n=i&63; int gk=kb+k;
    t[k][n] = (gk<INDIM) ? f2b(w1[(size_t)gk*HIDN + nb + n]) : (u16t)0;
  }
  __syncthreads();
  for(int i=threadIdx.x;i<4096;i+=256){
    int n=i>>6, k=i&63;
    w1t[(size_t)(nb+n)*KPAD + kb + k] = t[k][n];
  }
}

// ------------- pack conv weights (f32 -> bf16, tap-major K) + biases (f32) -----
__global__ __launch_bounds__(256) void k_wconv(const float* qw,const float* kw,const float* vw,const float* fw,
                        const float* qb,const float* kb_,const float* vb,const float* fb,
                        u16t* __restrict__ wct, float* __restrict__ bias){
  int i = blockIdx.x*256+threadIdx.x;
  if(i < CMAP*KCONV){
    int oc=i/KCONV, kk=i%KCONV;
    int ic=kk&63, tap=kk>>6;              // kk = tap*64+ic
    const float* w; int ol=oc;
    if(oc<192) w=qw;
    else if(oc<384){w=kw; ol=oc-192;}
    else if(oc<576){w=vw; ol=oc-384;}
    else {w=fw; ol=oc-576;}
    wct[(size_t)oc*KCONV + kk] = f2b(w[(ol*64+ic)*9 + tap]);
  }
  if(i<CMAP){
    bias[i] = (i<192)? qb[i] : (i<384? kb_[i-192] : (i<576? vb[i-384] : fb[i-576]));
  }
}

// ---------------- im2col: A[pix][576] bf16, k=tap*64+ic ------------------------
__global__ __launch_bounds__(256) void k_im2col(const u16t* __restrict__ feat, u16t* __restrict__ A){
  int i = blockIdx.x*256+threadIdx.x;   // (pix, k8) : 8192*72
  if(i>=PIX*72) return;
  int k8=i%72, pix=i/72;
  int tap=k8/8, ic8=(k8&7)<<3;
  int x=pix&63, y=(pix>>6)&63, b=pix>>12;
  int yy=y+tap/3-1, xx=x+tap%3-1;
  uint4 v;
  if(yy>=0&&yy<HWS&&xx>=0&&xx<HWS) v = *(const uint4*)&feat[(size_t)(((b*HWS+yy)*HWS+xx)*ENCC)+ic8];
  else v = make_uint4(0u,0u,0u,0u);
  *(uint4*)&A[(size_t)pix*KCONV + tap*64 + ic8] = v;
}

// ------- 128x128-tile MFMA GEMM, BK=64 (validated R17 config) — conv only ------
__global__ __launch_bounds__(256) void k_gemm128(const u16t* __restrict__ A, int lda,
    const u16t* __restrict__ BT, int ldb, const float* __restrict__ bias,
    void* __restrict__ Cout, int ldc, int kslice, int mode){
  __shared__ __align__(16) u16t As[128*64];
  __shared__ __align__(16) u16t Bs[128*64];
  int m0 = blockIdx.x*128, n0 = blockIdx.y*128;
  int tid = threadIdx.x;
  int wave = tid>>6, lane = tid&63;
  int wm = wave>>1, wn = wave&1;
  int kg = lane>>4, l16 = lane&15;
  int kbeg = blockIdx.z*kslice, kend = kbeg+kslice;
  f32x4 acc[4][4] = {};
  for(int k0=kbeg;k0<kend;k0+=64){
    __syncthreads();
    #pragma unroll
    for(int j=0;j<4;j++){
      int seg = (wave*4+j)*64 + lane;     // 0..1023
      int row = seg>>3, qp = seg&7;
      int q = qp ^ (row&7);               // inverse swizzle on SOURCE
      GLOAD16(&A [(size_t)(m0+row)*lda + k0 + q*8], &As[(wave*4+j)*512]);
      GLOAD16(&BT[(size_t)(n0+row)*ldb + k0 + q*8], &Bs[(wave*4+j)*512]);
    }
    __syncthreads();
    #pragma unroll
    for(int kk=0;kk<2;kk++){
      int ks = kk*4 + kg;                 // k-seg 0..7 within row
      short8 a[4], b[4];
      #pragma unroll
      for(int mf=0;mf<4;mf++){
        int row = wm*64+mf*16+l16;
        a[mf] = *(const short8*)&As[row*64 + (ks^(row&7))*8];   // swizzled read
      }
      #pragma unroll
      for(int nf=0;nf<4;nf++){
        int row = wn*64+nf*16+l16;
        b[nf] = *(const short8*)&Bs[row*64 + (ks^(row&7))*8];
      }
      #pragma unroll
      for(int mf=0;mf<4;mf++)
        #pragma unroll
        for(int nf=0;nf<4;nf++)
          acc[mf][nf] = __builtin_amdgcn_mfma_f32_16x16x32_bf16(a[mf], b[nf], acc[mf][nf], 0,0,0);
    }
  }
  int l4 = lane>>4;
  if(mode==0){
    u16t* C16 = (u16t*)Cout;
    #pragma unroll
    for(int mf=0;mf<4;mf++){
      #pragma unroll
      for(int nf=0;nf<4;nf++){
        #pragma unroll
        for(int r=0;r<4;r++){
          int gm = m0 + wm*64 + mf*16 + l4*4 + r;
          int gn = n0 + wn*64 + nf*16 + l16;
          C16[(size_t)gm*ldc+gn] = f2b(acc[mf][nf][r] + bias[gn]);
        }
      }
    }
  } else {
    u16t* C16 = (u16t*)Cout + (size_t)blockIdx.z * (size_t)(gridDim.x*128) * ldc;
    #pragma unroll
    for(int mf=0;mf<4;mf++){
      #pragma unroll
      for(int nf=0;nf<4;nf++){
        #pragma unroll
        for(int r=0;r<4;r++){
          int gm = m0 + wm*64 + mf*16 + l4*4 + r;
          int gn = n0 + wn*64 + nf*16 + l16;
          C16[(size_t)gm*ldc+gn] = f2b(acc[mf][nf][r]);
        }
      }
    }
  }
}

// ------- MLP GEMM: BM=64 x BN=256 (full-N tile => F read ONCE), BK=64 ----------
__global__ __launch_bounds__(256) void k_gemmMLP(const u16t* __restrict__ A, int lda,
    const u16t* __restrict__ BT, int ldb, u16t* __restrict__ Cout, int kslice){
  __shared__ __align__(16) u16t As[64*64];    // 8 KB
  __shared__ __align__(16) u16t Bs[256*64];   // 32 KB
  int m0 = blockIdx.x*64;
  int tid = threadIdx.x;
  int wave = tid>>6, lane = tid&63;
  int kg = lane>>4, l16 = lane&15;
  int kbeg = blockIdx.z*kslice, kend = kbeg+kslice;
  f32x4 acc[4][4] = {};
  for(int k0=kbeg;k0<kend;k0+=64){
    __syncthreads();
    #pragma unroll
    for(int j=0;j<2;j++){
      int seg = (wave*2+j)*64 + lane;     // 0..511
      int row = seg>>3, qp = seg&7;
      int q = qp ^ (row&7);
      GLOAD16(&A[(size_t)(m0+row)*lda + k0 + q*8], &As[(wave*2+j)*512]);
    }
    #pragma unroll
    for(int j=0;j<8;j++){
      int seg = (wave*8+j)*64 + lane;     // 0..2047
      int row = seg>>3, qp = seg&7;
      int q = qp ^ (row&7);
      GLOAD16(&BT[(size_t)row*ldb + k0 + q*8], &Bs[(wave*8+j)*512]);
    }
    __syncthreads();
    #pragma unroll
    for(int kk=0;kk<2;kk++){
      int ks = kk*4 + kg;
      short8 a[4], b[4];
      #pragma unroll
      for(int mf=0;mf<4;mf++){
        int row = mf*16+l16;
        a[mf] = *(const short8*)&As[row*64 + (ks^(row&7))*8];
      }
      #pragma unroll
      for(int nf=0;nf<4;nf++){
        int row = wave*64+nf*16+l16;
        b[nf] = *(const short8*)&Bs[row*64 + (ks^(row&7))*8];
      }
      #pragma unroll
      for(int mf=0;mf<4;mf++)
        #pragma unroll
        for(int nf=0;nf<4;nf++)
          acc[mf][nf] = __builtin_amdgcn_mfma_f32_16x16x32_bf16(a[mf], b[nf], acc[mf][nf], 0,0,0);
    }
  }
  int l4 = lane>>4;
  u16t* C16 = Cout + (size_t)blockIdx.z * (size_t)(gridDim.x*64) * HIDN;
  #pragma unroll
  for(int mf=0;mf<4;mf++){
    #pragma unroll
    for(int nf=0;nf<4;nf++){
      #pragma unroll
      for(int r=0;r<4;r++){
        int gm = m0 + mf*16 + l4*4 + r;
        int gn = wave*64 + nf*16 + l16;
        C16[(size_t)gm*HIDN+gn] = f2b(acc[mf][nf][r]);
      }
    }
  }
}

// ------- fused split-K reduce (bf16 partials) + w2 head + residual -------------
__global__ __launch_bounds__(256) void k_redout(const u16t* __restrict__ hidp, const float* __restrict__ b1,
                      const float* __restrict__ w2, const float* __restrict__ b2v,
                      const float* __restrict__ inp, const float* __restrict__ coord,
                      float* __restrict__ outp, int M, int q0){
  int i = blockIdx.x*256+threadIdx.x;
  if(i>=M*64) return;
  int q=i>>6, lane=i&63, n4=lane*4;
  f32x4 acc = *(const f32x4*)&b1[n4];
  for(int s=0;s<SPLITK;s++){
    uint2 t = *(const uint2*)&hidp[((size_t)s*M + q)*HIDN + n4];
    acc.x += b2f((u16t)t.x); acc.y += b2f((u16t)(t.x>>16));
    acc.z += b2f((u16t)t.y); acc.w += b2f((u16t)(t.y>>16));
  }
  float h0=fmaxf(acc.x,0.f), h1=fmaxf(acc.y,0.f), h2=fmaxf(acc.z,0.f), h3=fmaxf(acc.w,0.f);
  float p0 = h0*w2[n4*3+0] + h1*w2[(n4+1)*3+0] + h2*w2[(n4+2)*3+0] + h3*w2[(n4+3)*3+0];
  float p1 = h0*w2[n4*3+1] + h1*w2[(n4+1)*3+1] + h2*w2[(n4+2)*3+1] + h3*w2[(n4+3)*3+1];
  float p2 = h0*w2[n4*3+2] + h1*w2[(n4+1)*3+2] + h2*w2[(n4+2)*3+2] + h3*w2[(n4+3)*3+2];
  #pragma unroll
  for(int m=1;m<64;m<<=1){
    p0 += __shfl_xor(p0, m);
    p1 += __shfl_xor(p1, m);
    p2 += __shfl_xor(p2, m);
  }
  if(lane<3){
    int qg = q0 + q;
    int j = lane;
    float accj = (j==0? p0 : (j==1? p1 : p2)) + b2v[j];
    int b=qg/QN;
    float cy=coord[qg*2], cx=coord[qg*2+1];
    float py=fminf(fmaxf(((cy+1.f)*64.f-1.f)*0.5f,0.f),63.f);
    float px=fminf(fmaxf(((cx+1.f)*64.f-1.f)*0.5f,0.f),63.f);
    float y0f=floorf(py), x0f=floorf(px);
    float wy=py-y0f, wx=px-x0f;
    int y0=(int)y0f, x0=(int)x0f;
    int y1=min(y0+1,63), x1=min(x0+1,63);
    const float* ip=&inp[(size_t)(b*3+j)*4096];
    float g00=ip[y0*64+x0], g01=ip[y0*64+x1];
    float g10=ip[y1*64+x0], g11=ip[y1*64+x1];
    float res=g00*(1.f-wy)*(1.f-wx)+g01*(1.f-wy)*wx+g10*wy*(1.f-wx)+g11*wy*wx;
    outp[qg*3+j]=accj+res;
  }
}

// --------- per-query features (Hermitian-half DFT + geometric phase) -----------
__global__ __launch_bounds__(256,8) void k_feat(const float* __restrict__ coord, const float* __restrict__ cell,
                       const u16t* __restrict__ maps, const float* __restrict__ pbw,
                       const float* __restrict__ pbb, const float* __restrict__ pew,
                       u16t* __restrict__ F, float* __restrict__ outAttn, int q0){
  __shared__ float q_lds[DIMC];
  __shared__ float relsy[RAW], relsx[RAW];
  __shared__ int   wbase[RAW];
  __shared__ float sa[RAW][NHEAD];
  __shared__ float fr_lds[RAW*FRP];
  __shared__ float c7t[49], s7t[49];    // product-indexed: [i*7+j] = tw((i*j)%7)
  __shared__ float pewf0[CFC], pewf1[CFC];
  __shared__ float pbwf0[NHEAD], pbwf1[NHEAD], pbbf[NHEAD];

  int qg = q0 + blockIdx.x;
  int b  = qg / QN;
  int tid = threadIdx.x;
  float cy = coord[qg*2], cx = coord[qg*2+1];
  const float lo = -1.0f + 1e-6f, hi = 1.0f - 1e-6f;
  float ccy = fminf(fmaxf(cy,lo),hi), ccx = fminf(fmaxf(cx,lo),hi);
  float pyq = ((ccy+1.f)*64.f - 1.f)*0.5f, pxq = ((ccx+1.f)*64.f - 1.f)*0.5f;
  int iy = (int)rintf(pyq), ix = (int)rintf(pxq);   // round half-even == jnp.round

  if(tid < RAW){
    int ki = tid/7, kj = tid%7;
    int yy = iy + ki - 3, xx = ix + kj - 3;
    wbase[tid] = (yy>=0&&yy<64&&xx>=0&&xx<64) ? ((b*64+yy)*64+xx)*CMAP : -1;
    float ck_y = (-1.f + (float)(2*iy+1)*(1.f/64.f)) + (float)(ki-3)*(2.f/64.f);
    float ck_x = (-1.f + (float)(2*ix+1)*(1.f/64.f)) + (float)(kj-3)*(2.f/64.f);
    relsy[tid] = (cy - ck_y)*64.f;
    relsx[tid] = (cx - ck_x)*64.f;
    int m = (ki*kj)%7;
    float ang = -6.283185307179586f * (float)m / 7.f;
    c7t[tid]=cosf(ang); s7t[tid]=sinf(ang);
  }
  if(tid<CFC){ pewf0[tid]=pew[tid]; pewf1[tid]=pew[CFC+tid]; }
  if(tid<NHEAD){ pbwf0[tid]=pbw[tid]; pbwf1[tid]=pbw[NHEAD+tid]; pbbf[tid]=pbb[tid]; }
  __syncthreads();

  // q: bilinear-zeros gather of fq (maps ch [0,192), bf16)
  if(tid < DIMC){
    float y0f=floorf(pyq), x0f=floorf(pxq);
    float wy=pyq-y0f, wx=pxq-x0f;
    int y0=(int)y0f, x0=(int)x0f;
    float acc=0.f;
    for(int ty=0;ty<2;ty++) for(int tx=0;tx<2;tx++){
      int yy=y0+ty, xx=x0+tx;
      if(yy<0||yy>=64||xx<0||xx>=64) continue;
      float w=(ty? wy:1.f-wy)*(tx? wx:1.f-wx);
      acc += w * b2f(maps[(size_t)((b*64+yy)*64+xx)*CMAP + tid]);
    }
    q_lds[tid]=acc;
  }
  // fr load (maps ch [576,640), bf16, uint4 = 8ch -> 2x f32x4 into padded rows)
  for(int i=tid;i<RAW*8;i+=256){
    int k=i>>3, c8=(i&7)<<3;
    int base=wbase[k];
    f32x4 lo4={0.f,0.f,0.f,0.f}, hi4={0.f,0.f,0.f,0.f};
    if(base>=0){
      uint4 t = *(const uint4*)&maps[(size_t)base + 576 + c8];
      lo4 = f32x4{b2f((u16t)t.x), b2f((u16t)(t.x>>16)), b2f((u16t)t.y), b2f((u16t)(t.y>>16))};
      hi4 = f32x4{b2f((u16t)t.z), b2f((u16t)(t.z>>16)), b2f((u16t)t.w), b2f((u16t)(t.w>>16))};
    }
    *(f32x4*)&fr_lds[k*FRP+c8]   = lo4;
    *(f32x4*)&fr_lds[k*FRP+c8+4] = hi4;
  }
  __syncthreads();

  // sim + positional bias (k maps ch [192,384), bf16)
  for(int i=tid;i<RAW*NHEAD;i+=256){
    int k=i>>3, h=i&7;
    int base=wbase[k];
    float dot=0.f;
    if(base>=0){
      const u16t* p = &maps[(size_t)base + DIMC + h*DKH];
      for(int c8=0;c8<3;c8++){
        uint4 t = *(const uint4*)&p[c8*8];
        u32t a4[4]={t.x,t.y,t.z,t.w};
        for(int j=0;j<4;j++){
          dot += q_lds[h*DKH + c8*8 + 2*j]   * b2f((u16t)a4[j]);
          dot += q_lds[h*DKH + c8*8 + 2*j+1] * b2f((u16t)(a4[j]>>16));
        }
      }
    }
    sa[k][h] = dot/sqrtf(24.f) + relsy[k]*pbwf0[h] + relsx[k]*pbwf1[h] + pbbf[h];
  }
  __syncthreads();

  // wave-parallel softmax over k per head: 8 lanes per head, shfl_xor reduce
  if(tid < 64){
    int h = tid>>3, sub = tid&7;
    float m = -1e30f;
    for(int k=sub;k<RAW;k+=8) m = fmaxf(m, sa[k][h]);
    #pragma unroll
    for(int mm=1;mm<8;mm<<=1) m = fmaxf(m, __shfl_xor(m, mm));
    float s = 0.f;
    for(int k=sub;k<RAW;k+=8){ float e=__expf(sa[k][h]-m); sa[k][h]=e; s+=e; }
    #pragma unroll
    for(int mm=1;mm<8;mm<<=1) s += __shfl_xor(s, mm);
    float inv = 1.f/s;
    for(int k=sub;k<RAW;k+=8) sa[k][h]*=inv;
  }
  __syncthreads();
  if(qg==10 && tid<RAW) outAttn[tid] = sa[tid][0];

  size_t frow = (size_t)(qg-q0)*KPAD;
  // v * attn  (maps ch [384,576), bf16) -> F[k*320 + 0..191], uint4 writes
  for(int i=tid;i<RAW*24;i+=256){
    int k=i/24, c8=(i%24)*8;
    int base=wbase[k];
    u32t o[4]={0,0,0,0};
    if(base>=0){
      uint4 t = *(const uint4*)&maps[(size_t)base + 384 + c8];
      u32t a4[4]={t.x,t.y,t.z,t.w};
      for(int j=0;j<4;j++){
        int c0=c8+2*j;
        u16t r0=f2b(b2f((u16t)a4[j])      * sa[k][ c0   /DKH]);
        u16t r1=f2b(b2f((u16t)(a4[j]>>16))* sa[k][(c0+1)/DKH]);
        o[j] = (u32t)r0 | ((u32t)r1<<16);
      }
    }
    *(uint4*)&F[frow + (size_t)k*320 + c8] = make_uint4(o[0],o[1],o[2],o[3]);
  }
  // tail: rel_cell + zero pad to KPAD (448 entries from INDIM-2)
  for(int idx=INDIM-2+tid; idx<KPAD; idx+=256){
    u16t v=0;
    if(idx==15680) v=f2b(cell[qg*2]*64.f);
    else if(idx==15681) v=f2b(cell[qg*2+1]*64.f);
    F[frow+idx]=v;
  }

  // --- Hermitian-half 7x7 DFT (ortho) + geometric-phase Fourier PE ------------
  // ph(u) along a column is arithmetic (step -2*pw0) => exp(i*ph) geometric.
  {
    int v_ = tid>>6, c = tid&63;          // 256 pairs, exactly 1/thread
    float Gr[7], Gi[7];
    #pragma unroll
    for(int a_=0;a_<7;a_++){
      float re=0.f, im=0.f;
      #pragma unroll
      for(int bb=0;bb<7;bb++){
        float f=fr_lds[(a_*7+bb)*FRP+c];
        float cc=c7t[v_*7+bb], ss=s7t[v_*7+bb];
        re += f*cc; im += f*ss;
      }
      Gr[a_]=re; Gi[a_]=im;
    }
    float pw0=pewf0[c], pw1=pewf1[c];
    int v2 = (7-v_)%7;
    float ry0 = relsy[0];
    float a0 = ry0*pw0 + relsx[v_]*pw1;   // ph at (u=0, v_)
    float b0 = ry0*pw0 + relsx[v2]*pw1;   // ph at (u2=0, v2)
    float wa = -2.f*pw0;                  // per-u phase step
    float Er, Ei, Br, Bi, Wr, Wi;
    __sincosf(a0, &Ei, &Er);
    __sincosf(b0, &Bi, &Br);
    __sincosf(wa, &Wi, &Wr);
    // W^6 via squarings
    float w2r = Wr*Wr - Wi*Wi,  w2i = 2.f*Wr*Wi;
    float w4r = w2r*w2r - w2i*w2i, w4i = 2.f*w2r*w2i;
    float w6r = w4r*w2r - w4i*w2i, w6i = w4r*w2i + w4i*w2r;
    float E2r = Br, E2i = Bi;             // E2(0) = B
    int umax = (v_==0) ? 4 : 7;
    for(int u=0;u<umax;u++){
      float tr=0.f, ti=0.f;
      #pragma unroll
      for(int a_=0;a_<7;a_++){
        float cc=c7t[u*7+a_], ss=s7t[u*7+a_];
        tr += Gr[a_]*cc - Gi[a_]*ss;
        ti += Gr[a_]*ss + Gi[a_]*cc;
      }
      tr*=(1.f/7.f); ti*=(1.f/7.f);
      // direct output at k = u*7 + v_ (exp(i ph)*(tr+i ti))
      {
        int k = u*7 + v_;
        float er = Er*tr - Ei*ti, ei = Er*ti + Ei*tr;
        u32t pk = (u32t)f2b(er) | ((u32t)f2b(ei)<<16);
        *(u32t*)&F[frow + (size_t)k*320 + 192 + 2*c] = pk;
      }
      // conjugate partner at (u2,v2)=((7-u)%7, v2): (tr, -ti) rotated by E2
      if(!(v_==0 && u==0)){
        int u2 = (7-u)%7;
        int k2 = u2*7 + v2;
        float ti2 = -ti;
        float er = E2r*tr - E2i*ti2, ei = E2r*ti2 + E2i*tr;
        u32t pk = (u32t)f2b(er) | ((u32t)f2b(ei)<<16);
        *(u32t*)&F[frow + (size_t)k2*320 + 192 + 2*c] = pk;
      }
      // advance recurrences
      { float nr = Er*Wr - Ei*Wi; Ei = Er*Wi + Ei*Wr; Er = nr; }
      if(u==0){ float nr = Br*w6r - Bi*w6i; E2i = Br*w6i + Bi*w6r; E2r = nr; }  // E2(1)=B*W^6
      else    { float nr = E2r*Wr + E2i*Wi; E2i = -E2r*Wi + E2i*Wr; E2r = nr; } // *= conj(W)
    }
  }
}

// ---------------- marker fill (order-detection failed): out = value ------------
__global__ __launch_bounds__(256) void k_mark(float* __restrict__ outp, int n, float val){
  int i = blockIdx.x*256+threadIdx.x;
  if(i<n) outp[i]=val;
}

extern "C" void kernel_launch(void* const* d_in, const int* in_sizes, int n_in,
                              void* d_out, int out_size, void* d_ws, size_t ws_size,
                              hipStream_t stream){
  int I_inp, I_coord, I_cell, I_encw, I_encb, I_qw, I_qb, I_kw, I_kb, I_vw, I_vb,
      I_fw, I_fb, I_pbw, I_pbb, I_pew, I_w1, I_b1, I_w2, I_b2;
  bool dictOrder = (n_in==20 && in_sizes[0]==24576 && in_sizes[1]==9216 && in_sizes[3]==1728
                    && in_sizes[5]==110592 && in_sizes[16]==4014592 && in_sizes[19]==3);
  bool sortOrder = (n_in==20 && in_sizes[0]==256 && in_sizes[1]==3 && in_sizes[8]==24576
                    && in_sizes[10]==110592 && in_sizes[18]==4014592 && in_sizes[19]==768);
  if(dictOrder){
    I_inp=0; I_coord=1; I_cell=2; I_encw=3; I_encb=4; I_qw=5; I_qb=6; I_kw=7; I_kb=8;
    I_vw=9; I_vb=10; I_fw=11; I_fb=12; I_pbw=13; I_pbb=14; I_pew=15; I_w1=16; I_b1=17; I_w2=18; I_b2=19;
  } else if(sortOrder){
    I_b1=0; I_b2=1; I_cell=2; I_coord=3; I_encb=4; I_encw=5; I_fb=6; I_fw=7; I_inp=8;
    I_kb=9; I_kw=10; I_pbb=11; I_pbw=12; I_pew=13; I_qb=14; I_qw=15; I_vb=16; I_vw=17; I_w1=18; I_w2=19;
  } else {
    float mark = (float)(n_in==20 ? in_sizes[0] : 1000000+n_in);
    k_mark<<<dim3((out_size+255)/256), dim3(256), 0, stream>>>((float*)d_out, out_size, mark);
    return;
  }

  const float* inp  =(const float*)d_in[I_inp];
  const float* coord=(const float*)d_in[I_coord];
  const float* cell =(const float*)d_in[I_cell];
  const float* enc_w=(const float*)d_in[I_encw];
  const float* enc_b=(const float*)d_in[I_encb];
  const float* qw=(const float*)d_in[I_qw];
  const float* qb=(const float*)d_in[I_qb];
  const float* kw=(const float*)d_in[I_kw];
  const float* kbp=(const float*)d_in[I_kb];
  const float* vw=(const float*)d_in[I_vw];
  const float* vb=(const float*)d_in[I_vb];
  const float* fw=(const float*)d_in[I_fw];
  const float* fb=(const float*)d_in[I_fb];
  const float* pbw=(const float*)d_in[I_pbw];
  const float* pbb=(const float*)d_in[I_pbb];
  const float* pew=(const float*)d_in[I_pew];
  const float* w1=(const float*)d_in[I_w1];
  const float* b1=(const float*)d_in[I_b1];
  const float* w2=(const float*)d_in[I_w2];
  const float* b2v=(const float*)d_in[I_b2];
  float* outp=(float*)d_out;

  char* ws=(char*)d_ws;
  size_t off=0;
  auto alloc=[&](size_t bytes){ size_t o=off; off=(off+bytes+255)&~(size_t)255; return o; };
  size_t o_feat = alloc((size_t)PIX*ENCC*2);                   // 1 MB  (bf16)
  size_t o_imc  = alloc((size_t)PIX*KCONV*2);                  // 9.4 MB (bf16)
  size_t o_wct  = alloc((size_t)CMAP*KCONV*2);                 // 0.74 MB
  size_t o_cb   = alloc((size_t)CMAP*4);                       // conv bias f32
  size_t o_maps = alloc((size_t)PIX*CMAP*2);                   // 10.5 MB (bf16)
  size_t o_w1t  = alloc((size_t)HIDN*KPAD*2);                  // 8.3 MB
  size_t fixed = off;
  size_t rem = (ws_size>fixed)? ws_size-fixed : 0;
  size_t perQ = (size_t)KPAD*2 + (size_t)SPLITK*HIDN*2;        // F + hidp(bf16) per query
  long long cq = (long long)(rem/perQ);
  int chunkQ = (int)((cq/128)*128);
  if(chunkQ>NQ) chunkQ=NQ;
  size_t o_F, o_hp;
  if(chunkQ>=128){
    o_F  = alloc((size_t)chunkQ*KPAD*2);
    o_hp = alloc((size_t)SPLITK*chunkQ*HIDN*2);
  } else {
    chunkQ = 128;                                              // alias imc (dead after conv GEMM)
    o_F  = o_imc;                                              // 128*KPAD*2 = 4.1 MB
    o_hp = (o_imc + (size_t)128*KPAD*2 + 255) & ~(size_t)255;  // +0.8 MB < 9.4 MB
  }

  u16t*  feat=(u16t*)(ws+o_feat);
  u16t*  imc =(u16t*)(ws+o_imc);
  u16t*  wct =(u16t*)(ws+o_wct);
  float* cbias=(float*)(ws+o_cb);
  u16t*  maps=(u16t*)(ws+o_maps);
  u16t*  w1t =(u16t*)(ws+o_w1t);
  u16t*  Fb  =(u16t*)(ws+o_F);
  u16t*  hidp=(u16t*)(ws+o_hp);

  k_w1t   <<<dim3(KPAD/64, HIDN/64), dim3(256), 0, stream>>>(w1, w1t);
  k_wconv <<<dim3((CMAP*KCONV+255)/256), dim3(256), 0, stream>>>(qw,kw,vw,fw,qb,kbp,vb,fb,wct,cbias);
  k_enc   <<<dim3((PIX*ENCC+255)/256), dim3(256), 0, stream>>>(inp,enc_w,enc_b,feat);
  k_im2col<<<dim3((PIX*72+255)/256), dim3(256), 0, stream>>>(feat,imc);
  k_gemm128<<<dim3(PIX/128, CMAP/128, 1), dim3(256), 0, stream>>>(imc, KCONV, wct, KCONV, cbias,
            (void*)maps, CMAP, KCONV, 0);

  for(int q0=0;q0<NQ;q0+=chunkQ){
    int nq = (NQ-q0 < chunkQ) ? (NQ-q0) : chunkQ;
    k_feat<<<dim3(nq), dim3(256), 0, stream>>>(coord,cell,maps,pbw,pbb,pew,Fb,outp+13824,q0);
    k_gemmMLP<<<dim3(nq/64, 1, SPLITK), dim3(256), 0, stream>>>(Fb, KPAD, w1t, KPAD, hidp, KSLICE);
    k_redout<<<dim3((nq*64+255)/256), dim3(256), 0, stream>>>(hidp, b1, w2, b2v, inp, coord,
            outp, nq, q0);
  }
}

// Round 27
// 169.342 us; speedup vs baseline: 1.0632x; 1.0070x over previous
//
#include <hip/hip_runtime.h>

typedef unsigned short u16t;
typedef unsigned int   u32t;
typedef __attribute__((ext_vector_type(8))) short short8;
typedef __attribute__((ext_vector_type(4))) float f32x4;

#define B_    2
#define QN    2304
#define NQ    4608
#define HWS   64
#define ENCC  64
#define DIMC  192
#define NHEAD 8
#define DKH   24
#define RAW   49
#define CFC   64
#define FRP   68       // padded fr_lds row stride (floats)
#define CMAP  640      // 192(q)+192(k)+192(v)+64(f)
#define KCONV 576      // 9*64, k = tap*64+ic
#define INDIM 15682
#define KPAD  16128    // F row stride (bf16), 252*64 = 12*1344
#define HIDN  256
#define PIX   8192     // B*64*64
#define SPLITK 12
#define KSLICE (KPAD/SPLITK)   // 1344 = 21*64

__device__ __forceinline__ float b2f(u16t u){ u32t v=((u32t)u)<<16; return __builtin_bit_cast(float,v); }
__device__ __forceinline__ u16t f2b(float f){ u32t v=__builtin_bit_cast(u32t,f); return (u16t)((v + 0x7FFFu + ((v>>16)&1u))>>16); }

#define GLOAD16(SRC, DST) __builtin_amdgcn_global_load_lds( \
  (const __attribute__((address_space(1))) unsigned int*)(const void*)(SRC), \
  (__attribute__((address_space(3))) unsigned int*)(void*)(DST), 16, 0, 0)

// ---------------- encoder conv 3->64 (f32 in), channel-last bf16 out -----------
__global__ __launch_bounds__(256) void k_enc(const float* __restrict__ inp, const float* __restrict__ ew,
                      const float* __restrict__ eb, u16t* __restrict__ feat){
  int i = blockIdx.x*256+threadIdx.x;
  if(i>=B_*HWS*HWS*ENCC) return;
  int oc=i&63, x=(i>>6)&63, y=(i>>12)&63, b=i>>18;
  float acc = eb[oc];
  for(int c=0;c<3;c++)
    for(int dy=0;dy<3;dy++){
      int yy=y+dy-1; if(yy<0||yy>=HWS) continue;
      for(int dx=0;dx<3;dx++){
        int xx=x+dx-1; if(xx<0||xx>=HWS) continue;
        acc += inp[((b*3+c)*HWS+yy)*HWS+xx] * ew[((oc*3+c)*3+dy)*3+dx];
      }
    }
  feat[i]=f2b(acc);
}

// ---------------- w1 transpose: w1[k][256] (f32) -> w1t[n][KPAD] (bf16, pad) ---
__global__ __launch_bounds__(256) void k_w1t(const float* __restrict__ w1, u16t* __restrict__ w1t){
  __shared__ u16t t[64][65];
  int kb = blockIdx.x*64, nb = blockIdx.y*64;
  for(int i=threadIdx.x;i<4096;i+=256){
    int k=i>>6, n=i&63; int gk=kb+k;
    t[k][n] = (gk<INDIM) ? f2b(w1[(size_t)gk*HIDN + nb + n]) : (u16t)0;
  }
  __syncthreads();
  for(int i=threadIdx.x;i<4096;i+=256){
    int n=i>>6, k=i&63;
    w1t[(size_t)(nb+n)*KPAD + kb + k] = t[k][n];
  }
}

// ------------- pack conv weights (f32 -> bf16, tap-major K) + biases (f32) -----
__global__ __launch_bounds__(256) void k_wconv(const float* qw,const float* kw,const float* vw,const float* fw,
                        const float* qb,const float* kb_,const float* vb,const float* fb,
                        u16t* __restrict__ wct, float* __restrict__ bias){
  int i = blockIdx.x*256+threadIdx.x;
  if(i < CMAP*KCONV){
    int oc=i/KCONV, kk=i%KCONV;
    int ic=kk&63, tap=kk>>6;              // kk = tap*64+ic
    const float* w; int ol=oc;
    if(oc<192) w=qw;
    else if(oc<384){w=kw; ol=oc-192;}
    else if(oc<576){w=vw; ol=oc-384;}
    else {w=fw; ol=oc-576;}
    wct[(size_t)oc*KCONV + kk] = f2b(w[(ol*64+ic)*9 + tap]);
  }
  if(i<CMAP){
    bias[i] = (i<192)? qb[i] : (i<384? kb_[i-192] : (i<576? vb[i-384] : fb[i-576]));
  }
}

// ------- conv GEMM with FUSED im2col A-staging (BK=64 == one tap/step) ---------
// A row (pix, tap) = 64 contiguous bf16 of feat[pix'] where pix' shifted by tap;
// OOB rows read a 256B zeroed scratch. Same XOR-8 both-sides swizzle as R17.
__global__ __launch_bounds__(256) void k_gemmconv(const u16t* __restrict__ feat,
    const u16t* __restrict__ BT, int ldb, const float* __restrict__ bias,
    const u16t* __restrict__ zbuf, u16t* __restrict__ Cout, int ldc){
  __shared__ __align__(16) u16t As[128*64];
  __shared__ __align__(16) u16t Bs[128*64];
  int m0 = blockIdx.x*128, n0 = blockIdx.y*128;
  int tid = threadIdx.x;
  int wave = tid>>6, lane = tid&63;
  int wm = wave>>1, wn = wave&1;
  int kg = lane>>4, l16 = lane&15;
  f32x4 acc[4][4] = {};
  for(int k0=0;k0<KCONV;k0+=64){
    int tap = k0>>6;                      // BK=64 step == one conv tap
    int dy = tap/3 - 1, dx = tap%3 - 1;
    __syncthreads();
    #pragma unroll
    for(int j=0;j<4;j++){
      int seg = (wave*4+j)*64 + lane;     // 0..1023
      int row = seg>>3, qp = seg&7;
      int q = qp ^ (row&7);               // inverse swizzle on SOURCE
      int pix = m0 + row;
      int x = pix&63, y = (pix>>6)&63, b = pix>>12;
      int yy = y+dy, xx = x+dx;
      const u16t* srcA = (yy>=0&&yy<HWS&&xx>=0&&xx<HWS)
        ? &feat[(size_t)(((b*HWS+yy)*HWS+xx)*ENCC) + q*8]
        : &zbuf[q*8];
      GLOAD16(srcA, &As[(wave*4+j)*512]);
      GLOAD16(&BT[(size_t)(n0+row)*ldb + k0 + q*8], &Bs[(wave*4+j)*512]);
    }
    __syncthreads();
    #pragma unroll
    for(int kk=0;kk<2;kk++){
      int ks = kk*4 + kg;                 // k-seg 0..7 within row
      short8 a[4], b[4];
      #pragma unroll
      for(int mf=0;mf<4;mf++){
        int row = wm*64+mf*16+l16;
        a[mf] = *(const short8*)&As[row*64 + (ks^(row&7))*8];   // swizzled read
      }
      #pragma unroll
      for(int nf=0;nf<4;nf++){
        int row = wn*64+nf*16+l16;
        b[nf] = *(const short8*)&Bs[row*64 + (ks^(row&7))*8];
      }
      #pragma unroll
      for(int mf=0;mf<4;mf++)
        #pragma unroll
        for(int nf=0;nf<4;nf++)
          acc[mf][nf] = __builtin_amdgcn_mfma_f32_16x16x32_bf16(a[mf], b[nf], acc[mf][nf], 0,0,0);
    }
  }
  int l4 = lane>>4;
  u16t* C16 = Cout;
  #pragma unroll
  for(int mf=0;mf<4;mf++){
    #pragma unroll
    for(int nf=0;nf<4;nf++){
      #pragma unroll
      for(int r=0;r<4;r++){
        int gm = m0 + wm*64 + mf*16 + l4*4 + r;
        int gn = n0 + wn*64 + nf*16 + l16;
        C16[(size_t)gm*ldc+gn] = f2b(acc[mf][nf][r] + bias[gn]);
      }
    }
  }
}

// ------- MLP GEMM: BM=64 x BN=256 (full-N tile => F read ONCE), BK=64 ----------
__global__ __launch_bounds__(256) void k_gemmMLP(const u16t* __restrict__ A, int lda,
    const u16t* __restrict__ BT, int ldb, u16t* __restrict__ Cout, int kslice){
  __shared__ __align__(16) u16t As[64*64];    // 8 KB
  __shared__ __align__(16) u16t Bs[256*64];   // 32 KB
  int m0 = blockIdx.x*64;
  int tid = threadIdx.x;
  int wave = tid>>6, lane = tid&63;
  int kg = lane>>4, l16 = lane&15;
  int kbeg = blockIdx.z*kslice, kend = kbeg+kslice;
  f32x4 acc[4][4] = {};
  for(int k0=kbeg;k0<kend;k0+=64){
    __syncthreads();
    #pragma unroll
    for(int j=0;j<2;j++){
      int seg = (wave*2+j)*64 + lane;     // 0..511
      int row = seg>>3, qp = seg&7;
      int q = qp ^ (row&7);
      GLOAD16(&A[(size_t)(m0+row)*lda + k0 + q*8], &As[(wave*2+j)*512]);
    }
    #pragma unroll
    for(int j=0;j<8;j++){
      int seg = (wave*8+j)*64 + lane;     // 0..2047
      int row = seg>>3, qp = seg&7;
      int q = qp ^ (row&7);
      GLOAD16(&BT[(size_t)row*ldb + k0 + q*8], &Bs[(wave*8+j)*512]);
    }
    __syncthreads();
    #pragma unroll
    for(int kk=0;kk<2;kk++){
      int ks = kk*4 + kg;
      short8 a[4], b[4];
      #pragma unroll
      for(int mf=0;mf<4;mf++){
        int row = mf*16+l16;
        a[mf] = *(const short8*)&As[row*64 + (ks^(row&7))*8];
      }
      #pragma unroll
      for(int nf=0;nf<4;nf++){
        int row = wave*64+nf*16+l16;
        b[nf] = *(const short8*)&Bs[row*64 + (ks^(row&7))*8];
      }
      #pragma unroll
      for(int mf=0;mf<4;mf++)
        #pragma unroll
        for(int nf=0;nf<4;nf++)
          acc[mf][nf] = __builtin_amdgcn_mfma_f32_16x16x32_bf16(a[mf], b[nf], acc[mf][nf], 0,0,0);
    }
  }
  int l4 = lane>>4;
  u16t* C16 = Cout + (size_t)blockIdx.z * (size_t)(gridDim.x*64) * HIDN;
  #pragma unroll
  for(int mf=0;mf<4;mf++){
    #pragma unroll
    for(int nf=0;nf<4;nf++){
      #pragma unroll
      for(int r=0;r<4;r++){
        int gm = m0 + mf*16 + l4*4 + r;
        int gn = wave*64 + nf*16 + l16;
        C16[(size_t)gm*HIDN+gn] = f2b(acc[mf][nf][r]);
      }
    }
  }
}

// ------- fused split-K reduce (bf16 partials) + w2 head + residual -------------
__global__ __launch_bounds__(256) void k_redout(const u16t* __restrict__ hidp, const float* __restrict__ b1,
                      const float* __restrict__ w2, const float* __restrict__ b2v,
                      const float* __restrict__ inp, const float* __restrict__ coord,
                      float* __restrict__ outp, int M, int q0){
  int i = blockIdx.x*256+threadIdx.x;
  if(i>=M*64) return;
  int q=i>>6, lane=i&63, n4=lane*4;
  f32x4 acc = *(const f32x4*)&b1[n4];
  for(int s=0;s<SPLITK;s++){
    uint2 t = *(const uint2*)&hidp[((size_t)s*M + q)*HIDN + n4];
    acc.x += b2f((u16t)t.x); acc.y += b2f((u16t)(t.x>>16));
    acc.z += b2f((u16t)t.y); acc.w += b2f((u16t)(t.y>>16));
  }
  float h0=fmaxf(acc.x,0.f), h1=fmaxf(acc.y,0.f), h2=fmaxf(acc.z,0.f), h3=fmaxf(acc.w,0.f);
  float p0 = h0*w2[n4*3+0] + h1*w2[(n4+1)*3+0] + h2*w2[(n4+2)*3+0] + h3*w2[(n4+3)*3+0];
  float p1 = h0*w2[n4*3+1] + h1*w2[(n4+1)*3+1] + h2*w2[(n4+2)*3+1] + h3*w2[(n4+3)*3+1];
  float p2 = h0*w2[n4*3+2] + h1*w2[(n4+1)*3+2] + h2*w2[(n4+2)*3+2] + h3*w2[(n4+3)*3+2];
  #pragma unroll
  for(int m=1;m<64;m<<=1){
    p0 += __shfl_xor(p0, m);
    p1 += __shfl_xor(p1, m);
    p2 += __shfl_xor(p2, m);
  }
  if(lane<3){
    int qg = q0 + q;
    int j = lane;
    float accj = (j==0? p0 : (j==1? p1 : p2)) + b2v[j];
    int b=qg/QN;
    float cy=coord[qg*2], cx=coord[qg*2+1];
    float py=fminf(fmaxf(((cy+1.f)*64.f-1.f)*0.5f,0.f),63.f);
    float px=fminf(fmaxf(((cx+1.f)*64.f-1.f)*0.5f,0.f),63.f);
    float y0f=floorf(py), x0f=floorf(px);
    float wy=py-y0f, wx=px-x0f;
    int y0=(int)y0f, x0=(int)x0f;
    int y1=min(y0+1,63), x1=min(x0+1,63);
    const float* ip=&inp[(size_t)(b*3+j)*4096];
    float g00=ip[y0*64+x0], g01=ip[y0*64+x1];
    float g10=ip[y1*64+x0], g11=ip[y1*64+x1];
    float res=g00*(1.f-wy)*(1.f-wx)+g01*(1.f-wy)*wx+g10*wy*(1.f-wx)+g11*wy*wx;
    outp[qg*3+j]=accj+res;
  }
}

// --------- per-query features (Hermitian-half DFT + geometric phase) -----------
__global__ __launch_bounds__(256,8) void k_feat(const float* __restrict__ coord, const float* __restrict__ cell,
                       const u16t* __restrict__ maps, const float* __restrict__ pbw,
                       const float* __restrict__ pbb, const float* __restrict__ pew,
                       u16t* __restrict__ F, float* __restrict__ outAttn, int q0){
  __shared__ float q_lds[DIMC];
  __shared__ float relsy[RAW], relsx[RAW];
  __shared__ int   wbase[RAW];
  __shared__ float sa[RAW][NHEAD];
  __shared__ float fr_lds[RAW*FRP];
  __shared__ float c7t[49], s7t[49];    // product-indexed: [i*7+j] = tw((i*j)%7)
  __shared__ float pewf0[CFC], pewf1[CFC];
  __shared__ float pbwf0[NHEAD], pbwf1[NHEAD], pbbf[NHEAD];

  int qg = q0 + blockIdx.x;
  int b  = qg / QN;
  int tid = threadIdx.x;
  float cy = coord[qg*2], cx = coord[qg*2+1];
  const float lo = -1.0f + 1e-6f, hi = 1.0f - 1e-6f;
  float ccy = fminf(fmaxf(cy,lo),hi), ccx = fminf(fmaxf(cx,lo),hi);
  float pyq = ((ccy+1.f)*64.f - 1.f)*0.5f, pxq = ((ccx+1.f)*64.f - 1.f)*0.5f;
  int iy = (int)rintf(pyq), ix = (int)rintf(pxq);   // round half-even == jnp.round

  if(tid < RAW){
    int ki = tid/7, kj = tid%7;
    int yy = iy + ki - 3, xx = ix + kj - 3;
    wbase[tid] = (yy>=0&&yy<64&&xx>=0&&xx<64) ? ((b*64+yy)*64+xx)*CMAP : -1;
    float ck_y = (-1.f + (float)(2*iy+1)*(1.f/64.f)) + (float)(ki-3)*(2.f/64.f);
    float ck_x = (-1.f + (float)(2*ix+1)*(1.f/64.f)) + (float)(kj-3)*(2.f/64.f);
    relsy[tid] = (cy - ck_y)*64.f;
    relsx[tid] = (cx - ck_x)*64.f;
    int m = (ki*kj)%7;
    float ang = -6.283185307179586f * (float)m / 7.f;
    c7t[tid]=cosf(ang); s7t[tid]=sinf(ang);
  }
  if(tid<CFC){ pewf0[tid]=pew[tid]; pewf1[tid]=pew[CFC+tid]; }
  if(tid<NHEAD){ pbwf0[tid]=pbw[tid]; pbwf1[tid]=pbw[NHEAD+tid]; pbbf[tid]=pbb[tid]; }
  __syncthreads();

  // q: bilinear-zeros gather of fq (maps ch [0,192), bf16)
  if(tid < DIMC){
    float y0f=floorf(pyq), x0f=floorf(pxq);
    float wy=pyq-y0f, wx=pxq-x0f;
    int y0=(int)y0f, x0=(int)x0f;
    float acc=0.f;
    for(int ty=0;ty<2;ty++) for(int tx=0;tx<2;tx++){
      int yy=y0+ty, xx=x0+tx;
      if(yy<0||yy>=64||xx<0||xx>=64) continue;
      float w=(ty? wy:1.f-wy)*(tx? wx:1.f-wx);
      acc += w * b2f(maps[(size_t)((b*64+yy)*64+xx)*CMAP + tid]);
    }
    q_lds[tid]=acc;
  }
  // fr load (maps ch [576,640), bf16, uint4 = 8ch -> 2x f32x4 into padded rows)
  for(int i=tid;i<RAW*8;i+=256){
    int k=i>>3, c8=(i&7)<<3;
    int base=wbase[k];
    f32x4 lo4={0.f,0.f,0.f,0.f}, hi4={0.f,0.f,0.f,0.f};
    if(base>=0){
      uint4 t = *(const uint4*)&maps[(size_t)base + 576 + c8];
      lo4 = f32x4{b2f((u16t)t.x), b2f((u16t)(t.x>>16)), b2f((u16t)t.y), b2f((u16t)(t.y>>16))};
      hi4 = f32x4{b2f((u16t)t.z), b2f((u16t)(t.z>>16)), b2f((u16t)t.w), b2f((u16t)(t.w>>16))};
    }
    *(f32x4*)&fr_lds[k*FRP+c8]   = lo4;
    *(f32x4*)&fr_lds[k*FRP+c8+4] = hi4;
  }
  __syncthreads();

  // sim + positional bias (k maps ch [192,384), bf16)
  for(int i=tid;i<RAW*NHEAD;i+=256){
    int k=i>>3, h=i&7;
    int base=wbase[k];
    float dot=0.f;
    if(base>=0){
      const u16t* p = &maps[(size_t)base + DIMC + h*DKH];
      for(int c8=0;c8<3;c8++){
        uint4 t = *(const uint4*)&p[c8*8];
        u32t a4[4]={t.x,t.y,t.z,t.w};
        for(int j=0;j<4;j++){
          dot += q_lds[h*DKH + c8*8 + 2*j]   * b2f((u16t)a4[j]);
          dot += q_lds[h*DKH + c8*8 + 2*j+1] * b2f((u16t)(a4[j]>>16));
        }
      }
    }
    sa[k][h] = dot/sqrtf(24.f) + relsy[k]*pbwf0[h] + relsx[k]*pbwf1[h] + pbbf[h];
  }
  __syncthreads();

  // wave-parallel softmax over k per head: 8 lanes per head, shfl_xor reduce
  if(tid < 64){
    int h = tid>>3, sub = tid&7;
    float m = -1e30f;
    for(int k=sub;k<RAW;k+=8) m = fmaxf(m, sa[k][h]);
    #pragma unroll
    for(int mm=1;mm<8;mm<<=1) m = fmaxf(m, __shfl_xor(m, mm));
    float s = 0.f;
    for(int k=sub;k<RAW;k+=8){ float e=__expf(sa[k][h]-m); sa[k][h]=e; s+=e; }
    #pragma unroll
    for(int mm=1;mm<8;mm<<=1) s += __shfl_xor(s, mm);
    float inv = 1.f/s;
    for(int k=sub;k<RAW;k+=8) sa[k][h]*=inv;
  }
  __syncthreads();
  if(qg==10 && tid<RAW) outAttn[tid] = sa[tid][0];

  size_t frow = (size_t)(qg-q0)*KPAD;
  // v * attn  (maps ch [384,576), bf16) -> F[k*320 + 0..191], uint4 writes
  for(int i=tid;i<RAW*24;i+=256){
    int k=i/24, c8=(i%24)*8;
    int base=wbase[k];
    u32t o[4]={0,0,0,0};
    if(base>=0){
      uint4 t = *(const uint4*)&maps[(size_t)base + 384 + c8];
      u32t a4[4]={t.x,t.y,t.z,t.w};
      for(int j=0;j<4;j++){
        int c0=c8+2*j;
        u16t r0=f2b(b2f((u16t)a4[j])      * sa[k][ c0   /DKH]);
        u16t r1=f2b(b2f((u16t)(a4[j]>>16))* sa[k][(c0+1)/DKH]);
        o[j] = (u32t)r0 | ((u32t)r1<<16);
      }
    }
    *(uint4*)&F[frow + (size_t)k*320 + c8] = make_uint4(o[0],o[1],o[2],o[3]);
  }
  // tail: rel_cell + zero pad to KPAD (448 entries from INDIM-2)
  for(int idx=INDIM-2+tid; idx<KPAD; idx+=256){
    u16t v=0;
    if(idx==15680) v=f2b(cell[qg*2]*64.f);
    else if(idx==15681) v=f2b(cell[qg*2+1]*64.f);
    F[frow+idx]=v;
  }

  // --- Hermitian-half 7x7 DFT (ortho) + geometric-phase Fourier PE ------------
  {
    int v_ = tid>>6, c = tid&63;          // 256 pairs, exactly 1/thread
    float Gr[7], Gi[7];
    #pragma unroll
    for(int a_=0;a_<7;a_++){
      float re=0.f, im=0.f;
      #pragma unroll
      for(int bb=0;bb<7;bb++){
        float f=fr_lds[(a_*7+bb)*FRP+c];
        float cc=c7t[v_*7+bb], ss=s7t[v_*7+bb];
        re += f*cc; im += f*ss;
      }
      Gr[a_]=re; Gi[a_]=im;
    }
    float pw0=pewf0[c], pw1=pewf1[c];
    int v2 = (7-v_)%7;
    float ry0 = relsy[0];
    float a0 = ry0*pw0 + relsx[v_]*pw1;   // ph at (u=0, v_)
    float b0 = ry0*pw0 + relsx[v2]*pw1;   // ph at (u2=0, v2)
    float wa = -2.f*pw0;                  // per-u phase step
    float Er, Ei, Br, Bi, Wr, Wi;
    __sincosf(a0, &Ei, &Er);
    __sincosf(b0, &Bi, &Br);
    __sincosf(wa, &Wi, &Wr);
    float w2r = Wr*Wr - Wi*Wi,  w2i = 2.f*Wr*Wi;
    float w4r = w2r*w2r - w2i*w2i, w4i = 2.f*w2r*w2i;
    float w6r = w4r*w2r - w4i*w2i, w6i = w4r*w2i + w4i*w2r;
    float E2r = Br, E2i = Bi;             // E2(0) = B
    int umax = (v_==0) ? 4 : 7;
    for(int u=0;u<umax;u++){
      float tr=0.f, ti=0.f;
      #pragma unroll
      for(int a_=0;a_<7;a_++){
        float cc=c7t[u*7+a_], ss=s7t[u*7+a_];
        tr += Gr[a_]*cc - Gi[a_]*ss;
        ti += Gr[a_]*ss + Gi[a_]*cc;
      }
      tr*=(1.f/7.f); ti*=(1.f/7.f);
      {
        int k = u*7 + v_;
        float er = Er*tr - Ei*ti, ei = Er*ti + Ei*tr;
        u32t pk = (u32t)f2b(er) | ((u32t)f2b(ei)<<16);
        *(u32t*)&F[frow + (size_t)k*320 + 192 + 2*c] = pk;
      }
      if(!(v_==0 && u==0)){
        int u2 = (7-u)%7;
        int k2 = u2*7 + v2;
        float ti2 = -ti;
        float er = E2r*tr - E2i*ti2, ei = E2r*ti2 + E2i*tr;
        u32t pk = (u32t)f2b(er) | ((u32t)f2b(ei)<<16);
        *(u32t*)&F[frow + (size_t)k2*320 + 192 + 2*c] = pk;
      }
      { float nr = Er*Wr - Ei*Wi; Ei = Er*Wi + Ei*Wr; Er = nr; }
      if(u==0){ float nr = Br*w6r - Bi*w6i; E2i = Br*w6i + Bi*w6r; E2r = nr; }
      else    { float nr = E2r*Wr + E2i*Wi; E2i = -E2r*Wi + E2i*Wr; E2r = nr; }
    }
  }
}

// ---------------- marker fill (order-detection failed): out = value ------------
__global__ __launch_bounds__(256) void k_mark(float* __restrict__ outp, int n, float val){
  int i = blockIdx.x*256+threadIdx.x;
  if(i<n) outp[i]=val;
}

extern "C" void kernel_launch(void* const* d_in, const int* in_sizes, int n_in,
                              void* d_out, int out_size, void* d_ws, size_t ws_size,
                              hipStream_t stream){
  int I_inp, I_coord, I_cell, I_encw, I_encb, I_qw, I_qb, I_kw, I_kb, I_vw, I_vb,
      I_fw, I_fb, I_pbw, I_pbb, I_pew, I_w1, I_b1, I_w2, I_b2;
  bool dictOrder = (n_in==20 && in_sizes[0]==24576 && in_sizes[1]==9216 && in_sizes[3]==1728
                    && in_sizes[5]==110592 && in_sizes[16]==4014592 && in_sizes[19]==3);
  bool sortOrder = (n_in==20 && in_sizes[0]==256 && in_sizes[1]==3 && in_sizes[8]==24576
                    && in_sizes[10]==110592 && in_sizes[18]==4014592 && in_sizes[19]==768);
  if(dictOrder){
    I_inp=0; I_coord=1; I_cell=2; I_encw=3; I_encb=4; I_qw=5; I_qb=6; I_kw=7; I_kb=8;
    I_vw=9; I_vb=10; I_fw=11; I_fb=12; I_pbw=13; I_pbb=14; I_pew=15; I_w1=16; I_b1=17; I_w2=18; I_b2=19;
  } else if(sortOrder){
    I_b1=0; I_b2=1; I_cell=2; I_coord=3; I_encb=4; I_encw=5; I_fb=6; I_fw=7; I_inp=8;
    I_kb=9; I_kw=10; I_pbb=11; I_pbw=12; I_pew=13; I_qb=14; I_qw=15; I_vb=16; I_vw=17; I_w1=18; I_w2=19;
  } else {
    float mark = (float)(n_in==20 ? in_sizes[0] : 1000000+n_in);
    k_mark<<<dim3((out_size+255)/256), dim3(256), 0, stream>>>((float*)d_out, out_size, mark);
    return;
  }

  const float* inp  =(const float*)d_in[I_inp];
  const float* coord=(const float*)d_in[I_coord];
  const float* cell =(const float*)d_in[I_cell];
  const float* enc_w=(const float*)d_in[I_encw];
  const float* enc_b=(const float*)d_in[I_encb];
  const float* qw=(const float*)d_in[I_qw];
  const float* qb=(const float*)d_in[I_qb];
  const float* kw=(const float*)d_in[I_kw];
  const float* kbp=(const float*)d_in[I_kb];
  const float* vw=(const float*)d_in[I_vw];
  const float* vb=(const float*)d_in[I_vb];
  const float* fw=(const float*)d_in[I_fw];
  const float* fb=(const float*)d_in[I_fb];
  const float* pbw=(const float*)d_in[I_pbw];
  const float* pbb=(const float*)d_in[I_pbb];
  const float* pew=(const float*)d_in[I_pew];
  const float* w1=(const float*)d_in[I_w1];
  const float* b1=(const float*)d_in[I_b1];
  const float* w2=(const float*)d_in[I_w2];
  const float* b2v=(const float*)d_in[I_b2];
  float* outp=(float*)d_out;

  char* ws=(char*)d_ws;
  size_t off=0;
  auto alloc=[&](size_t bytes){ size_t o=off; off=(off+bytes+255)&~(size_t)255; return o; };
  size_t o_feat = alloc((size_t)PIX*ENCC*2);                   // 1 MB  (bf16)
  size_t o_spare= alloc((size_t)PIX*KCONV*2);                  // 9.4 MB (zero-buf + F fallback)
  size_t o_wct  = alloc((size_t)CMAP*KCONV*2);                 // 0.74 MB
  size_t o_cb   = alloc((size_t)CMAP*4);                       // conv bias f32
  size_t o_maps = alloc((size_t)PIX*CMAP*2);                   // 10.5 MB (bf16)
  size_t o_w1t  = alloc((size_t)HIDN*KPAD*2);                  // 8.3 MB
  size_t fixed = off;
  size_t rem = (ws_size>fixed)? ws_size-fixed : 0;
  size_t perQ = (size_t)KPAD*2 + (size_t)SPLITK*HIDN*2;        // F + hidp(bf16) per query
  long long cq = (long long)(rem/perQ);
  int chunkQ = (int)((cq/128)*128);
  if(chunkQ>NQ) chunkQ=NQ;
  size_t o_F, o_hp;
  if(chunkQ>=128){
    o_F  = alloc((size_t)chunkQ*KPAD*2);
    o_hp = alloc((size_t)SPLITK*chunkQ*HIDN*2);
  } else {
    chunkQ = 128;                                              // alias spare (dead zone past zero-buf)
    o_F  = o_spare + 4096;                                     // 128*KPAD*2 = 4.1 MB
    o_hp = (o_F + (size_t)128*KPAD*2 + 255) & ~(size_t)255;    // +0.8 MB < 9.4 MB
  }

  u16t*  feat=(u16t*)(ws+o_feat);
  u16t*  zbuf=(u16t*)(ws+o_spare);                             // 256B zeroed below
  u16t*  wct =(u16t*)(ws+o_wct);
  float* cbias=(float*)(ws+o_cb);
  u16t*  maps=(u16t*)(ws+o_maps);
  u16t*  w1t =(u16t*)(ws+o_w1t);
  u16t*  Fb  =(u16t*)(ws+o_F);
  u16t*  hidp=(u16t*)(ws+o_hp);

  hipMemsetAsync(zbuf, 0, 256, stream);                        // OOB source for k_gemmconv
  k_w1t   <<<dim3(KPAD/64, HIDN/64), dim3(256), 0, stream>>>(w1, w1t);
  k_wconv <<<dim3((CMAP*KCONV+255)/256), dim3(256), 0, stream>>>(qw,kw,vw,fw,qb,kbp,vb,fb,wct,cbias);
  k_enc   <<<dim3((PIX*ENCC+255)/256), dim3(256), 0, stream>>>(inp,enc_w,enc_b,feat);
  k_gemmconv<<<dim3(PIX/128, CMAP/128, 1), dim3(256), 0, stream>>>(feat, wct, KCONV, cbias,
            zbuf, maps, CMAP);

  for(int q0=0;q0<NQ;q0+=chunkQ){
    int nq = (NQ-q0 < chunkQ) ? (NQ-q0) : chunkQ;
    k_feat<<<dim3(nq), dim3(256), 0, stream>>>(coord,cell,maps,pbw,pbb,pew,Fb,outp+13824,q0);
    k_gemmMLP<<<dim3(nq/64, 1, SPLITK), dim3(256), 0, stream>>>(Fb, KPAD, w1t, KPAD, hidp, KSLICE);
    k_redout<<<dim3((nq*64+255)/256), dim3(256), 0, stream>>>(hidp, b1, w2, b2v, inp, coord,
            outp, nq, q0);
  }
}